// Round 6
// baseline (451.999 us; speedup 1.0000x reference)
//
#include <hip/hip_runtime.h>
#include <math.h>

// ---------------- problem constants ----------------
#define TSEQ 2048
#define DD   512
#define NH   8
#define HSZ  64
#define NE   8
#define NTOK 8192    // B*T
#define CAPK 2048
#define FF   2048    // 4*D

typedef __bf16 bf16x8 __attribute__((ext_vector_type(8)));
typedef float  f32x4  __attribute__((ext_vector_type(4)));
typedef unsigned int u32;
typedef u32 u32x4 __attribute__((ext_vector_type(4)));

__device__ __forceinline__ void gload16(const void* g, void* l){
  __builtin_amdgcn_global_load_lds((const __attribute__((address_space(1))) u32*)g,
                                   (__attribute__((address_space(3))) u32*)l, 16, 0, 0);
}

__device__ __forceinline__ u32 pkbf(float a, float b){
  unsigned short ua = __builtin_bit_cast(unsigned short, (__bf16)a);
  unsigned short ub = __builtin_bit_cast(unsigned short, (__bf16)b);
  return (u32)ua | ((u32)ub << 16);
}

// ============================================================
// Threefry-2x32, key = (0, 42)
// ============================================================
__device__ __forceinline__ unsigned rotl32(unsigned x, int r){ return (x<<r)|(x>>(32-r)); }

__device__ __forceinline__ void threefry2x32(unsigned c0, unsigned c1, unsigned &o0, unsigned &o1){
  const unsigned k0 = 0u, k1 = 42u;
  const unsigned k2 = k0 ^ k1 ^ 0x1BD11BDAu;
  unsigned x0 = c0 + k0, x1 = c1 + k1;
#define TFR(rot) { x0 += x1; x1 = rotl32(x1, rot); x1 ^= x0; }
  TFR(13) TFR(15) TFR(26) TFR(6)   x0 += k1; x1 += k2 + 1u;
  TFR(17) TFR(29) TFR(16) TFR(24)  x0 += k2; x1 += k0 + 2u;
  TFR(13) TFR(15) TFR(26) TFR(6)   x0 += k0; x1 += k1 + 3u;
  TFR(17) TFR(29) TFR(16) TFR(24)  x0 += k1; x1 += k2 + 4u;
  TFR(13) TFR(15) TFR(26) TFR(6)   x0 += k2; x1 += k0 + 5u;
#undef TFR
  o0 = x0; o1 = x1;
}

__device__ __forceinline__ float erfinv_f(float x){
  float w = -log1pf(-x*x);
  float p;
  if (w < 5.0f){
    w -= 2.5f;
    p = 2.81022636e-08f;
    p = fmaf(p,w, 3.43273939e-07f);
    p = fmaf(p,w,-3.5233877e-06f);
    p = fmaf(p,w,-4.39150654e-06f);
    p = fmaf(p,w, 0.00021858087f);
    p = fmaf(p,w,-0.00125372503f);
    p = fmaf(p,w,-0.00417768164f);
    p = fmaf(p,w, 0.246640727f);
    p = fmaf(p,w, 1.50140941f);
  } else {
    w = sqrtf(w) - 3.0f;
    p = -0.000200214257f;
    p = fmaf(p,w, 0.000100950558f);
    p = fmaf(p,w, 0.00134934322f);
    p = fmaf(p,w,-0.00367342844f);
    p = fmaf(p,w, 0.00573950773f);
    p = fmaf(p,w,-0.0076224613f);
    p = fmaf(p,w, 0.00943887047f);
    p = fmaf(p,w, 1.00167406f);
    p = fmaf(p,w, 2.83297682f);
  }
  return p * x;
}

// ============================================================
// LayerNorm -> hi/lo bf16 (LN1)
// ============================================================
__global__ __launch_bounds__(256) void ln_split(const float* __restrict__ x,
    const float* __restrict__ gw, const float* __restrict__ bw,
    __bf16* __restrict__ ohi, __bf16* __restrict__ olo)
{
  int row  = blockIdx.x*4 + threadIdx.y;
  int lane = threadIdx.x;
  const float* xr = x + (size_t)row*DD;
  float4 a = *(const float4*)(xr + lane*4);
  float4 c = *(const float4*)(xr + 256 + lane*4);
  float s  = a.x+a.y+a.z+a.w + c.x+c.y+c.z+c.w;
  float ss = a.x*a.x+a.y*a.y+a.z*a.z+a.w*a.w + c.x*c.x+c.y*c.y+c.z*c.z+c.w*c.w;
  #pragma unroll
  for (int off = 32; off; off >>= 1){ s += __shfl_xor(s, off); ss += __shfl_xor(ss, off); }
  float m   = s * (1.0f/DD);
  float var = ss * (1.0f/DD) - m*m;
  float r   = 1.0f / sqrtf(var + 1e-5f);
  float4 g1 = *(const float4*)(gw + lane*4);
  float4 b1 = *(const float4*)(bw + lane*4);
  float4 g2 = *(const float4*)(gw + 256 + lane*4);
  float4 b2 = *(const float4*)(bw + 256 + lane*4);
  float f1[4], f2[4];
  f1[0]=(a.x-m)*r*g1.x+b1.x; f1[1]=(a.y-m)*r*g1.y+b1.y; f1[2]=(a.z-m)*r*g1.z+b1.z; f1[3]=(a.w-m)*r*g1.w+b1.w;
  f2[0]=(c.x-m)*r*g2.x+b2.x; f2[1]=(c.y-m)*r*g2.y+b2.y; f2[2]=(c.z-m)*r*g2.z+b2.z; f2[3]=(c.w-m)*r*g2.w+b2.w;
  __bf16 h1v[4] __attribute__((aligned(8))), l1v[4] __attribute__((aligned(8)));
  __bf16 h2v[4] __attribute__((aligned(8))), l2v[4] __attribute__((aligned(8)));
  #pragma unroll
  for (int j = 0; j < 4; ++j){
    __bf16 hb = (__bf16)f1[j]; h1v[j]=hb; l1v[j]=(__bf16)(f1[j]-(float)hb);
    __bf16 hc = (__bf16)f2[j]; h2v[j]=hc; l2v[j]=(__bf16)(f2[j]-(float)hc);
  }
  size_t base = (size_t)row*DD + lane*4;
  *(uint2*)(ohi + base)       = *(const uint2*)h1v;
  *(uint2*)(olo + base)       = *(const uint2*)l1v;
  *(uint2*)(ohi + base + 256) = *(const uint2*)h2v;
  *(uint2*)(olo + base + 256) = *(const uint2*)l2v;
}

// ============================================================
// Pack Wq|Wk|Wv (H,D,HS) -> transposed hi/lo bf16 [1536][512]
// ============================================================
__global__ __launch_bounds__(256) void pack_qkv_split(const float* __restrict__ Wq,
    const float* __restrict__ Wk, const float* __restrict__ Wv,
    __bf16* __restrict__ dhi, __bf16* __restrict__ dlo)
{
  __shared__ float t[64][65];
  int z = blockIdx.y;
  int kt = blockIdx.x*64;
  int sel = z >> 3, hh = z & 7;
  const float* W = (sel==0 ? Wq : (sel==1 ? Wk : Wv)) + (size_t)hh*DD*HSZ;
  int tid = threadIdx.x;
  int r = tid>>2, c0 = (tid&3)*16;
  #pragma unroll
  for (int j = 0; j < 16; j += 4){
    float4 v = *(const float4*)&W[(size_t)(kt+r)*HSZ + c0 + j];
    t[r][c0+j]=v.x; t[r][c0+j+1]=v.y; t[r][c0+j+2]=v.z; t[r][c0+j+3]=v.w;
  }
  __syncthreads();
  __bf16 hb[16] __attribute__((aligned(32)));
  __bf16 lb[16] __attribute__((aligned(32)));
  #pragma unroll
  for (int j = 0; j < 16; ++j){
    float f = t[c0+j][r];
    __bf16 h = (__bf16)f; hb[j]=h; lb[j]=(__bf16)(f-(float)h);
  }
  size_t off = (size_t)(z*64 + r)*512 + kt + c0;
  *(uint4*)(dhi+off) = ((const uint4*)hb)[0]; *(uint4*)(dhi+off+8) = ((const uint4*)hb)[1];
  *(uint4*)(dlo+off) = ((const uint4*)lb)[0]; *(uint4*)(dlo+off+8) = ((const uint4*)lb)[1];
}

// ============================================================
// Generic transpose + hi/lo split (Wo)
// ============================================================
__global__ __launch_bounds__(256) void transp_split(const float* __restrict__ src,
    __bf16* __restrict__ dhi, __bf16* __restrict__ dlo, int Ms, int Ns)
{
  __shared__ float t[64][65];
  int nt = blockIdx.x*64, mt = blockIdx.y*64;
  int tid = threadIdx.x;
  int r = tid>>2, c0 = (tid&3)*16;
  #pragma unroll
  for (int j = 0; j < 16; j += 4){
    float4 v = *(const float4*)&src[(size_t)(mt+r)*Ns + nt + c0 + j];
    t[r][c0+j]=v.x; t[r][c0+j+1]=v.y; t[r][c0+j+2]=v.z; t[r][c0+j+3]=v.w;
  }
  __syncthreads();
  __bf16 hb[16] __attribute__((aligned(32)));
  __bf16 lb[16] __attribute__((aligned(32)));
  #pragma unroll
  for (int j = 0; j < 16; ++j){
    float f = t[c0+j][r];
    __bf16 h = (__bf16)f; hb[j]=h; lb[j]=(__bf16)(f-(float)h);
  }
  size_t off = (size_t)(nt + r)*Ms + mt + c0;
  *(uint4*)(dhi+off) = ((const uint4*)hb)[0]; *(uint4*)(dhi+off+8) = ((const uint4*)hb)[1];
  *(uint4*)(dlo+off) = ((const uint4*)lb)[0]; *(uint4*)(dlo+off+8) = ((const uint4*)lb)[1];
}

// ============================================================
// bf16x3 split-precision MFMA GEMM, 2-phase double-buffered.
// MODE 0: C f32 = A@B^T + bias + res          (Wo projection)
// MODE 1: QKV epilogue -> pre-scaled Q hi/lo, K hi/lo, V^T hi/lo bf16
// ============================================================
template<int MODE>
__global__ __launch_bounds__(256) void gemm_mfma3(
    const __bf16* __restrict__ Ahi, const __bf16* __restrict__ Alo,
    const __bf16* __restrict__ Bhi, const __bf16* __restrict__ Blo,
    const float* __restrict__ bias, const float* __restrict__ res, float* __restrict__ C,
    __bf16* __restrict__ qh, __bf16* __restrict__ ql,
    __bf16* __restrict__ kh, __bf16* __restrict__ kl,
    __bf16* __restrict__ vth, __bf16* __restrict__ vtl,
    int M, int N, int K)
{
  __shared__ __bf16 AsH[2][4096];
  __shared__ __bf16 AsL[2][4096];
  __shared__ __bf16 BsH[2][4096];
  __shared__ __bf16 BsL[2][4096];
  int m0 = blockIdx.y*128, n0 = blockIdx.x*128;
  int tid = threadIdx.x;
  int w = tid>>6, l = tid&63;
  int wm = w>>1, wn = w&1;
  int srow = w*32 + (l>>2);
  int skb  = (l&3)<<4;
  const char* agh = (const char*)(Ahi + (size_t)(m0+srow)*K) + skb;
  const char* agl = (const char*)(Alo + (size_t)(m0+srow)*K) + skb;
  const char* bgh = (const char*)(Bhi + (size_t)(n0+srow)*K) + skb;
  const char* bgl = (const char*)(Blo + (size_t)(n0+srow)*K) + skb;
  size_t r16 = (size_t)16*K*sizeof(__bf16);

  f32x4 acc[4][4] = {};
  int rl = l & 15, kh_ = l >> 4;
  const __bf16* abh = &AsH[0][(wm*64 + rl)*32 + kh_*8];
  const __bf16* abl = &AsL[0][(wm*64 + rl)*32 + kh_*8];
  const __bf16* bbh = &BsH[0][(wn*64 + rl)*32 + kh_*8];
  const __bf16* bbl = &BsL[0][(wn*64 + rl)*32 + kh_*8];

  auto STAGE = [&](int bb, int kt){
    size_t o = (size_t)kt*64;
    gload16(agh+o,     &AsH[bb][w*1024]);
    gload16(agh+o+r16, &AsH[bb][w*1024+512]);
    gload16(agl+o,     &AsL[bb][w*1024]);
    gload16(agl+o+r16, &AsL[bb][w*1024+512]);
    gload16(bgh+o,     &BsH[bb][w*1024]);
    gload16(bgh+o+r16, &BsH[bb][w*1024+512]);
    gload16(bgl+o,     &BsL[bb][w*1024]);
    gload16(bgl+o+r16, &BsL[bb][w*1024+512]);
  };

  int nkt = K >> 5;
  STAGE(0, 0);
  __syncthreads();
  for (int kt = 0; kt < nkt; ++kt){
    int bb = kt & 1;
    if (kt + 1 < nkt) STAGE(bb^1, kt+1);
    bf16x8 afh[4], afl[4], bfh[4], bfl[4];
    #pragma unroll
    for (int i = 0; i < 4; ++i){
      afh[i] = *(const bf16x8*)(abh + bb*4096 + i*512);
      afl[i] = *(const bf16x8*)(abl + bb*4096 + i*512);
      bfh[i] = *(const bf16x8*)(bbh + bb*4096 + i*512);
      bfl[i] = *(const bf16x8*)(bbl + bb*4096 + i*512);
    }
    __builtin_amdgcn_s_setprio(1);
    #pragma unroll
    for (int fm = 0; fm < 4; ++fm)
      #pragma unroll
      for (int fn = 0; fn < 4; ++fn){
        acc[fm][fn] = __builtin_amdgcn_mfma_f32_16x16x32_bf16(afh[fm], bfl[fn], acc[fm][fn], 0, 0, 0);
        acc[fm][fn] = __builtin_amdgcn_mfma_f32_16x16x32_bf16(afl[fm], bfh[fn], acc[fm][fn], 0, 0, 0);
        acc[fm][fn] = __builtin_amdgcn_mfma_f32_16x16x32_bf16(afh[fm], bfh[fn], acc[fm][fn], 0, 0, 0);
      }
    __builtin_amdgcn_s_setprio(0);
    __syncthreads();
  }

  int ccol = l & 15, cr = (l >> 4) * 4;
  if (MODE == 0){
    #pragma unroll
    for (int fn = 0; fn < 4; ++fn){
      int n = n0 + wn*64 + fn*16 + ccol;
      float bv = bias[n];
      #pragma unroll
      for (int fm = 0; fm < 4; ++fm){
        int mb = m0 + wm*64 + fm*16 + cr;
        #pragma unroll
        for (int r = 0; r < 4; ++r){
          float v = acc[fm][fn][r] + bv + res[(size_t)(mb+r)*N + n];
          C[(size_t)(mb+r)*N + n] = v;
        }
      }
    }
  } else {
    // QKV epilogue: n in [0,512)=Q (pre-scaled), [512,1024)=K, [1024,1536)=V^T
    int b = m0 >> 11;
    int tb = (m0 & 2047) + wm*64 + cr;
    int sel = n0 >> 9;                      // uniform per block (128 | 512)
    const float qsc = 0.04419417382415922f * 1.4426950408889634f;  // D^-0.5 * log2(e)
    #pragma unroll
    for (int fn = 0; fn < 4; ++fn){
      int n = n0 + wn*64 + fn*16 + ccol;
      int hh = (n >> 6) & 7, e = n & 63;
      size_t bh = (size_t)(b*8 + hh);
      #pragma unroll
      for (int fm = 0; fm < 4; ++fm){
        int t0 = tb + fm*16;
        if (sel == 2){
          __bf16 hv[4] __attribute__((aligned(8))), lv[4] __attribute__((aligned(8)));
          #pragma unroll
          for (int r = 0; r < 4; ++r){
            float v = acc[fm][fn][r];
            __bf16 hb = (__bf16)v; hv[r] = hb; lv[r] = (__bf16)(v - (float)hb);
          }
          size_t off = (bh*64 + e)*TSEQ + t0;
          *(uint2*)(vth + off) = *(const uint2*)hv;
          *(uint2*)(vtl + off) = *(const uint2*)lv;
        } else {
          __bf16* dh = sel ? kh : qh;
          __bf16* dl = sel ? kl : ql;
          float sc = sel ? 1.0f : qsc;
          #pragma unroll
          for (int r = 0; r < 4; ++r){
            float v = acc[fm][fn][r] * sc;
            __bf16 hb = (__bf16)v;
            size_t off = (bh*TSEQ + t0 + r)*64 + e;
            dh[off] = hb; dl[off] = (__bf16)(v - (float)hb);
          }
        }
      }
    }
  }
}

// ============================================================
// bf16 MFMA GEMM (experts), 2-phase double-buffered.
// ============================================================
template<int STORE_BF16, int RELU>
__global__ __launch_bounds__(256) void gemm_mfma(
    const __bf16* __restrict__ A, const __bf16* __restrict__ Bt,
    const float* __restrict__ bias, void* __restrict__ Cv,
    int M, int N, int K)
{
  __shared__ __bf16 Asl[2][4096];
  __shared__ __bf16 Bsl[2][4096];
  int e = blockIdx.z;
  const __bf16* Ae = A  + (size_t)e*M*K;
  const __bf16* Be = Bt + (size_t)e*N*K;
  const float*  be = bias + (size_t)e*N;
  int m0 = blockIdx.y*128, n0 = blockIdx.x*128;
  int tid = threadIdx.x;
  int w = tid>>6, l = tid&63;
  int wm = w>>1, wn = w&1;
  int srow = w*32 + (l>>2);
  int skb  = (l&3)<<4;
  const char* ag = (const char*)(Ae + (size_t)(m0 + srow)*K) + skb;
  const char* bg = (const char*)(Be + (size_t)(n0 + srow)*K) + skb;
  size_t r16 = (size_t)16*K*sizeof(__bf16);

  f32x4 acc[4][4] = {};
  int rl = l & 15, kh = l >> 4;
  const __bf16* abase = &Asl[0][(wm*64 + rl)*32 + kh*8];
  const __bf16* bbase = &Bsl[0][(wn*64 + rl)*32 + kh*8];

  auto STAGE = [&](int bb, int kt){
    size_t o = (size_t)kt*64;
    gload16(ag+o,     &Asl[bb][w*1024]);
    gload16(ag+o+r16, &Asl[bb][w*1024+512]);
    gload16(bg+o,     &Bsl[bb][w*1024]);
    gload16(bg+o+r16, &Bsl[bb][w*1024+512]);
  };

  int nkt = K >> 5;
  STAGE(0, 0);
  __syncthreads();
  for (int kt = 0; kt < nkt; ++kt){
    int bb = kt & 1;
    if (kt + 1 < nkt) STAGE(bb^1, kt+1);
    bf16x8 af[4], bf[4];
    #pragma unroll
    for (int i = 0; i < 4; ++i){
      af[i] = *(const bf16x8*)(abase + bb*4096 + i*512);
      bf[i] = *(const bf16x8*)(bbase + bb*4096 + i*512);
    }
    __builtin_amdgcn_s_setprio(1);
    #pragma unroll
    for (int fm = 0; fm < 4; ++fm)
      #pragma unroll
      for (int fn = 0; fn < 4; ++fn)
        acc[fm][fn] = __builtin_amdgcn_mfma_f32_16x16x32_bf16(af[fm], bf[fn], acc[fm][fn], 0, 0, 0);
    __builtin_amdgcn_s_setprio(0);
    __syncthreads();
  }

  int ccol = l & 15, cr = (l >> 4) * 4;
  char* Ce = (char*)Cv + (size_t)e*M*N*(STORE_BF16 ? 2 : 4);
  #pragma unroll
  for (int fn = 0; fn < 4; ++fn){
    int n = n0 + wn*64 + fn*16 + ccol;
    float bv = be[n];
    #pragma unroll
    for (int fm = 0; fm < 4; ++fm){
      int mb = m0 + wm*64 + fm*16 + cr;
      #pragma unroll
      for (int r = 0; r < 4; ++r){
        float v = acc[fm][fn][r] + bv;
        if (RELU) v = fmaxf(v, 0.f);
        if (STORE_BF16) ((__bf16*)Ce)[(size_t)(mb+r)*N + n] = (__bf16)v;
        else            ((float*)Ce)[(size_t)(mb+r)*N + n] = v;
      }
    }
  }
}

// ============================================================
// Transpose + convert expert weights (f32 -> plain bf16 [N][K])
// ============================================================
__global__ __launch_bounds__(256) void transp_conv(const float* __restrict__ src,
    __bf16* __restrict__ dst, int Ms, int Ns)
{
  __shared__ __bf16 t[64][72];
  int e = blockIdx.z;
  const float* s = src + (size_t)e*Ms*Ns;
  __bf16* d = dst + (size_t)e*Ms*Ns;
  int mt = blockIdx.y*64, nt = blockIdx.x*64;
  int tid = threadIdx.x;
  int r = tid>>2, c0 = (tid&3)*16;
  #pragma unroll
  for (int j = 0; j < 16; j += 4){
    float4 v = *(const float4*)&s[(size_t)(mt+r)*Ns + nt + c0 + j];
    t[r][c0+j]   = (__bf16)v.x; t[r][c0+j+1] = (__bf16)v.y;
    t[r][c0+j+2] = (__bf16)v.z; t[r][c0+j+3] = (__bf16)v.w;
  }
  __syncthreads();
  __bf16 tmp[16] __attribute__((aligned(32)));
  #pragma unroll
  for (int j = 0; j < 16; ++j) tmp[j] = t[c0+j][r];
  uint4* dp = (uint4*)&d[(size_t)(nt+r)*Ms + mt + c0];
  dp[0] = ((const uint4*)tmp)[0];
  dp[1] = ((const uint4*)tmp)[1];
}

// ============================================================
// bf16x3 MFMA flash attention (causal), transposed compute.
// All Q/K/V pre-split bf16 hi/lo (Q pre-scaled, exp2 domain).
// Load-balanced q-tile pairing; defer-max THR=8; setprio on MFMA.
// ============================================================
__global__ __launch_bounds__(512) void attn_mfma(
    const __bf16* __restrict__ qhi_g, const __bf16* __restrict__ qlo_g,
    const __bf16* __restrict__ khi_g, const __bf16* __restrict__ klo_g,
    const __bf16* __restrict__ vthi_g, const __bf16* __restrict__ vtlo_g,
    __bf16* __restrict__ ahi, __bf16* __restrict__ alo)
{
  __shared__ __align__(16) char ldsbuf[65536];   // [2 buf][4 arr][8KB]
  int bh = blockIdx.x;
  int qtA = blockIdx.y, qtB = 15 - qtA;
  int b = bh >> 3;
  int tid = threadIdx.x;
  int w = tid >> 6, l = tid & 63;
  int g = l >> 4, r = l & 15;
  int sA = r + 32*(g & 1);
  int sB = sA + 16;
  int ghalf = g >> 1;

  int qb[2]; qb[0] = qtA*128 + w*16; qb[1] = qtB*128 + (7-w)*16;
  int kdiag[2]; kdiag[0] = qb[0] >> 6; kdiag[1] = qb[1] >> 6;

  // ---- persistent Q fragments (pre-scaled hi/lo bf16) ----
  bf16x8 qhi[2][2], qlo[2][2];
  #pragma unroll
  for (int qf = 0; qf < 2; ++qf)
    #pragma unroll
    for (int ks = 0; ks < 2; ++ks){
      size_t qoff = ((size_t)bh*TSEQ + qb[qf] + r)*64 + ks*32 + g*8;
      qhi[qf][ks] = *(const bf16x8*)(qhi_g + qoff);
      qlo[qf][ks] = *(const bf16x8*)(qlo_g + qoff);
    }

  f32x4 ot[4][2] = {};
  float m_r[2] = {-INFINITY, -INFINITY};
  float l_r[2] = {0.f, 0.f};

  int nkt = 2*qtB + 2;
  size_t kbase = (size_t)bh*TSEQ*64;
  size_t vbase = (size_t)bh*64*TSEQ;

  auto STAGE = [&](int buf, int kt){
    int row = tid >> 3, cc = tid & 7;
    int sw = (cc ^ (row & 7)) * 8;
    char* d = ldsbuf + buf*32768 + (w << 10);
    gload16(khi_g  + kbase + (size_t)(kt*64 + row)*64 + sw, d);
    gload16(klo_g  + kbase + (size_t)(kt*64 + row)*64 + sw, d + 8192);
    gload16(vthi_g + vbase + (size_t)row*TSEQ + kt*64 + sw,  d + 16384);
    gload16(vtlo_g + vbase + (size_t)row*TSEQ + kt*64 + sw,  d + 24576);
  };

  STAGE(0, 0);
  __syncthreads();

  for (int kt = 0; kt < nkt; ++kt){
    int buf = kt & 1;
    if (kt + 1 < nkt) STAGE(buf ^ 1, kt + 1);

    bool act[2];
    act[0] = (kt <= kdiag[0]);
    act[1] = (kt <= kdiag[1]);

    const char* K0 = ldsbuf + buf*32768;
    const char* K1 = K0 + 8192;
    const char* V0 = K0 + 16384;
    const char* V1 = K0 + 24576;

    // ---- S^T = K · Q^T (bf16x3) ----
    f32x4 s[4][2] = {};
    __builtin_amdgcn_s_setprio(1);
    #pragma unroll
    for (int kf = 0; kf < 4; ++kf){
      int rowk = kf*16 + r;
      int rsw = (rowk & 7) << 4;
      #pragma unroll
      for (int ks = 0; ks < 2; ++ks){
        int off = rowk*128 + ((((ks*4 + g) << 4)) ^ rsw);
        bf16x8 khf = *(const bf16x8*)(K0 + off);
        bf16x8 klf = *(const bf16x8*)(K1 + off);
        #pragma unroll
        for (int qf = 0; qf < 2; ++qf){
          if (act[qf]){
            s[kf][qf] = __builtin_amdgcn_mfma_f32_16x16x32_bf16(khf, qlo[qf][ks], s[kf][qf], 0,0,0);
            s[kf][qf] = __builtin_amdgcn_mfma_f32_16x16x32_bf16(klf, qhi[qf][ks], s[kf][qf], 0,0,0);
            s[kf][qf] = __builtin_amdgcn_mfma_f32_16x16x32_bf16(khf, qhi[qf][ks], s[kf][qf], 0,0,0);
          }
        }
      }
    }
    __builtin_amdgcn_s_setprio(0);

    // ---- mask (diag tile only) + online softmax (exp2, defer-max THR=8) ----
    u32 phi[4][2][2], plo[4][2][2];
    #pragma unroll
    for (int qf = 0; qf < 2; ++qf){
      if (act[qf]){
        int q = qb[qf] + r;
        float p[4][4];
        float mx = -INFINITY;
        if (kt == kdiag[qf]){
          #pragma unroll
          for (int kf = 0; kf < 4; ++kf)
            #pragma unroll
            for (int e = 0; e < 4; ++e){
              int key = kt*64 + kf*16 + g*4 + e;
              float sv = (key <= q) ? s[kf][qf][e] : -INFINITY;
              p[kf][e] = sv;
              mx = fmaxf(mx, sv);
            }
        } else {
          #pragma unroll
          for (int kf = 0; kf < 4; ++kf)
            #pragma unroll
            for (int e = 0; e < 4; ++e){
              float sv = s[kf][qf][e];
              p[kf][e] = sv;
              mx = fmaxf(mx, sv);
            }
        }
        mx = fmaxf(mx, __shfl_xor(mx, 16));
        mx = fmaxf(mx, __shfl_xor(mx, 32));
        if (__any(mx > m_r[qf] + 8.0f)){          // defer-max (T13)
          float mn = fmaxf(m_r[qf], mx);
          float fj = exp2f(m_r[qf] - mn);
          m_r[qf] = mn;
          l_r[qf] *= fj;
          #pragma unroll
          for (int ef = 0; ef < 4; ++ef)
            #pragma unroll
            for (int e = 0; e < 4; ++e)
              ot[ef][qf][e] *= fj;
        }
        float ts = 0.f;
        #pragma unroll
        for (int kf = 0; kf < 4; ++kf)
          #pragma unroll
          for (int e = 0; e < 4; ++e){
            float pv = exp2f(p[kf][e] - m_r[qf]);
            p[kf][e] = pv; ts += pv;
          }
        ts += __shfl_xor(ts, 16); ts += __shfl_xor(ts, 32);
        l_r[qf] += ts;
        #pragma unroll
        for (int kf = 0; kf < 4; ++kf){
          __bf16 h0=(__bf16)p[kf][0], h1=(__bf16)p[kf][1], h2=(__bf16)p[kf][2], h3=(__bf16)p[kf][3];
          phi[kf][qf][0] = pkbf(p[kf][0], p[kf][1]);
          phi[kf][qf][1] = pkbf(p[kf][2], p[kf][3]);
          plo[kf][qf][0] = pkbf(p[kf][0]-(float)h0, p[kf][1]-(float)h1);
          plo[kf][qf][1] = pkbf(p[kf][2]-(float)h2, p[kf][3]-(float)h3);
        }
      }
    }

    // ---- O^T += V^T · P^T (bf16x3); P^T B-frags via shuffles ----
    #pragma unroll
    for (int ks = 0; ks < 2; ++ks){
      u32x4 pbh[2], pbl[2];
      #pragma unroll
      for (int qf = 0; qf < 2; ++qf){
        if (act[qf]){
          #pragma unroll
          for (int p2 = 0; p2 < 2; ++p2){
            u32 hA0 = (u32)__shfl((int)phi[2*ks  ][qf][p2], sA);
            u32 hA1 = (u32)__shfl((int)phi[2*ks+1][qf][p2], sA);
            u32 hB0 = (u32)__shfl((int)phi[2*ks  ][qf][p2], sB);
            u32 hB1 = (u32)__shfl((int)phi[2*ks+1][qf][p2], sB);
            pbh[qf][p2]   = ghalf ? hA1 : hA0;
            pbh[qf][2+p2] = ghalf ? hB1 : hB0;
            u32 lA0 = (u32)__shfl((int)plo[2*ks  ][qf][p2], sA);
            u32 lA1 = (u32)__shfl((int)plo[2*ks+1][qf][p2], sA);
            u32 lB0 = (u32)__shfl((int)plo[2*ks  ][qf][p2], sB);
            u32 lB1 = (u32)__shfl((int)plo[2*ks+1][qf][p2], sB);
            pbl[qf][p2]   = ghalf ? lA1 : lA0;
            pbl[qf][2+p2] = ghalf ? lB1 : lB0;
          }
        }
      }
      __builtin_amdgcn_s_setprio(1);
      #pragma unroll
      for (int ef = 0; ef < 4; ++ef){
        int rowv = ef*16 + r;
        int off = rowv*128 + ((((ks*4 + g) << 4)) ^ ((rowv & 7) << 4));
        bf16x8 vhf = *(const bf16x8*)(V0 + off);
        bf16x8 vlf = *(const bf16x8*)(V1 + off);
        #pragma unroll
        for (int qf = 0; qf < 2; ++qf){
          if (act[qf]){
            bf16x8 ph = __builtin_bit_cast(bf16x8, pbh[qf]);
            bf16x8 pl = __builtin_bit_cast(bf16x8, pbl[qf]);
            ot[ef][qf] = __builtin_amdgcn_mfma_f32_16x16x32_bf16(vhf, pl, ot[ef][qf], 0,0,0);
            ot[ef][qf] = __builtin_amdgcn_mfma_f32_16x16x32_bf16(vlf, ph, ot[ef][qf], 0,0,0);
            ot[ef][qf] = __builtin_amdgcn_mfma_f32_16x16x32_bf16(vhf, ph, ot[ef][qf], 0,0,0);
          }
        }
      }
      __builtin_amdgcn_s_setprio(0);
    }
    __syncthreads();
  }

  // ---- epilogue: per q-tile O^T -> LDS transpose -> hi/lo bf16 store ----
  float* Osh = (float*)ldsbuf;   // [128][68]
  #pragma unroll
  for (int qf = 0; qf < 2; ++qf){
    float inv = 1.0f / l_r[qf];
    int qloc = (qf ? (7-w) : w)*16 + r;
    #pragma unroll
    for (int ef = 0; ef < 4; ++ef)
      #pragma unroll
      for (int e = 0; e < 4; ++e)
        Osh[qloc*68 + ef*16 + g*4 + e] = ot[ef][qf][e] * inv;
    __syncthreads();
    {
      int qt = qf ? qtB : qtA;
      int q = tid >> 2, e0 = (tid & 3)*16;
      const float* srow = Osh + q*68 + e0;
      int h = bh & 7;
      size_t base = ((size_t)(b*TSEQ + qt*128 + q))*DD + h*64 + e0;
      #pragma unroll
      for (int j = 0; j < 4; ++j){
        float4 v = *(const float4*)(srow + j*4);
        float f[4] = {v.x, v.y, v.z, v.w};
        __bf16 hb[4] __attribute__((aligned(8)));
        __bf16 lb[4] __attribute__((aligned(8)));
        #pragma unroll
        for (int q2 = 0; q2 < 4; ++q2){
          __bf16 h2b = (__bf16)f[q2];
          hb[q2] = h2b; lb[q2] = (__bf16)(f[q2] - (float)h2b);
        }
        *(uint2*)(ahi + base + j*4) = *(const uint2*)hb;
        *(uint2*)(alo + base + j*4) = *(const uint2*)lb;
      }
    }
    __syncthreads();
  }
}

// ============================================================
// Fused LN2 + Router: reads x1, writes h2 (bf16) + routing
// ============================================================
__global__ __launch_bounds__(256) void routerln_kernel(const float* __restrict__ x1,
    const float* __restrict__ gw, const float* __restrict__ bw,
    const float* __restrict__ Wg, const float* __restrict__ bg,
    const float* __restrict__ Wn, const float* __restrict__ bn,
    __bf16* __restrict__ h2b,
    int* __restrict__ idx0, int* __restrict__ idx1,
    float* __restrict__ g0, float* __restrict__ g1)
{
  int wid = threadIdx.x >> 6, lane = threadIdx.x & 63;
  int tok = blockIdx.x*4 + wid;
  const float* xr = x1 + (size_t)tok*DD;
  float4 a = *(const float4*)(xr + lane*4);
  float4 c = *(const float4*)(xr + 256 + lane*4);
  float s  = a.x+a.y+a.z+a.w + c.x+c.y+c.z+c.w;
  float ss = a.x*a.x+a.y*a.y+a.z*a.z+a.w*a.w + c.x*c.x+c.y*c.y+c.z*c.z+c.w*c.w;
  #pragma unroll
  for (int off = 32; off; off >>= 1){ s += __shfl_xor(s, off); ss += __shfl_xor(ss, off); }
  float m   = s * (1.0f/DD);
  float var = ss * (1.0f/DD) - m*m;
  float rr  = 1.0f / sqrtf(var + 1e-5f);
  float4 g1v = *(const float4*)(gw + lane*4);
  float4 b1v = *(const float4*)(bw + lane*4);
  float4 g2v = *(const float4*)(gw + 256 + lane*4);
  float4 b2v = *(const float4*)(bw + 256 + lane*4);
  float f1[4], f2[4];
  f1[0]=(a.x-m)*rr*g1v.x+b1v.x; f1[1]=(a.y-m)*rr*g1v.y+b1v.y; f1[2]=(a.z-m)*rr*g1v.z+b1v.z; f1[3]=(a.w-m)*rr*g1v.w+b1v.w;
  f2[0]=(c.x-m)*rr*g2v.x+b2v.x; f2[1]=(c.y-m)*rr*g2v.y+b2v.y; f2[2]=(c.z-m)*rr*g2v.z+b2v.z; f2[3]=(c.w-m)*rr*g2v.w+b2v.w;
  // write h2 (bf16)
  {
    __bf16 h1v[4] __attribute__((aligned(8)));
    __bf16 h2v[4] __attribute__((aligned(8)));
    #pragma unroll
    for (int j = 0; j < 4; ++j){ h1v[j] = (__bf16)f1[j]; h2v[j] = (__bf16)f2[j]; }
    size_t base = (size_t)tok*DD + lane*4;
    *(uint2*)(h2b + base)       = *(const uint2*)h1v;
    *(uint2*)(h2b + base + 256) = *(const uint2*)h2v;
  }
  // logits (f32)
  float ag[8] = {0,0,0,0,0,0,0,0}, an[8] = {0,0,0,0,0,0,0,0};
  int d1 = lane*4, d2 = 256 + lane*4;
  #pragma unroll
  for (int j = 0; j < 4; ++j){
    const float* wg1 = Wg + (size_t)(d1+j)*8;
    const float* wn1 = Wn + (size_t)(d1+j)*8;
    const float* wg2 = Wg + (size_t)(d2+j)*8;
    const float* wn2 = Wn + (size_t)(d2+j)*8;
    #pragma unroll
    for (int e = 0; e < 8; ++e){
      ag[e] = fmaf(f1[j], wg1[e], ag[e]); an[e] = fmaf(f1[j], wn1[e], an[e]);
      ag[e] = fmaf(f2[j], wg2[e], ag[e]); an[e] = fmaf(f2[j], wn2[e], an[e]);
    }
  }
  #pragma unroll
  for (int off = 32; off; off >>= 1){
    #pragma unroll
    for (int e = 0; e < 8; ++e){ ag[e] += __shfl_xor(ag[e], off); an[e] += __shfl_xor(an[e], off); }
  }
  __shared__ float ns[4][8];
  if (lane < 8){
    int e = lane;
    float lg = ag[e] + bg[e];
    float nl = an[e] + bn[e];
    float sp = fmaxf(nl, 0.f) + log1pf(expf(-fabsf(nl)));
    unsigned i = (unsigned)(tok*8 + e);
    unsigned r0b, r1b;
    threefry2x32(0u, i, r0b, r1b);
    unsigned bits = r0b ^ r1b;
    float f = __uint_as_float((bits >> 9) | 0x3f800000u) - 1.0f;
    float u = fmaf(f, 2.0f, -0.99999994f);
    u = fmaxf(u, -0.99999994f);
    float z = 1.41421356f * erfinv_f(u);
    ns[wid][e] = lg + z*sp;
  }
  __syncthreads();
  if (lane == 0){
    float v0 = -INFINITY; int i0 = 0;
    #pragma unroll
    for (int e = 0; e < 8; ++e){ float v = ns[wid][e]; if (v > v0){ v0 = v; i0 = e; } }
    float v1 = -INFINITY; int i1 = 0;
    #pragma unroll
    for (int e = 0; e < 8; ++e){ if (e != i0){ float v = ns[wid][e]; if (v > v1){ v1 = v; i1 = e; } } }
    float dexp = expf(v1 - v0);
    float ssum = 1.0f + dexp;
    idx0[tok] = i0; idx1[tok] = i1;
    g0[tok] = 1.0f/ssum; g1[tok] = dexp/ssum;
  }
}

// ============================================================
// Capacity routing
// ============================================================
__global__ __launch_bounds__(256) void route_scan(const int* __restrict__ idx0,
    const int* __restrict__ idx1, int* __restrict__ idx_buf, int* __restrict__ tok_slot)
{
  int e = blockIdx.x, tid = threadIdx.x;
  for (int i = tid; i < CAPK; i += 256) idx_buf[e*CAPK + i] = 0;
  __syncthreads();
  int base = tid * 32;
  int cnt = 0;
  for (int j = 0; j < 32; ++j){ int t = base + j; cnt += (idx0[t]==e || idx1[t]==e) ? 1 : 0; }
  __shared__ int ps[256];
  ps[tid] = cnt; __syncthreads();
  for (int off = 1; off < 256; off <<= 1){
    int add = (tid >= off) ? ps[tid - off] : 0;
    __syncthreads();
    ps[tid] += add;
    __syncthreads();
  }
  int slot = ps[tid] - cnt;
  for (int j = 0; j < 32; ++j){
    int t = base + j;
    int k = (idx0[t]==e) ? 0 : ((idx1[t]==e) ? 1 : -1);
    if (k >= 0){
      if (slot < CAPK){ idx_buf[e*CAPK + slot] = t; tok_slot[t*2 + k] = slot; }
      else            { tok_slot[t*2 + k] = -1; }
      slot++;
    }
  }
}

// ============================================================
// Gather (bf16 copy)
// ============================================================
__global__ __launch_bounds__(128) void gather_b(const __bf16* __restrict__ h2b,
    const int* __restrict__ idx_buf, __bf16* __restrict__ xg)
{
  int ec = blockIdx.x;
  int tok = idx_buf[ec];
  ((uint2*)(xg + (size_t)ec*DD))[threadIdx.x] =
      ((const uint2*)(h2b + (size_t)tok*DD))[threadIdx.x];
}

// ============================================================
// Combine (eout bf16)
// ============================================================
__global__ __launch_bounds__(128) void combine_kernel(const float* __restrict__ x1,
    const __bf16* __restrict__ eout, const int* __restrict__ idx0, const int* __restrict__ idx1,
    const float* __restrict__ g0, const float* __restrict__ g1,
    const int* __restrict__ tok_slot, float* __restrict__ outp)
{
  int n = blockIdx.x, t = threadIdx.x;
  float4 acc = *(const float4*)(x1 + (size_t)n*DD + t*4);
  #pragma unroll
  for (int k = 0; k < 2; ++k){
    int s = tok_slot[n*2 + k];
    if (s >= 0){
      int e  = (k==0) ? idx0[n] : idx1[n];
      float g = (k==0) ? g0[n] : g1[n];
      __bf16 vb[4] __attribute__((aligned(8)));
      *(uint2*)vb = *(const uint2*)(eout + ((size_t)(e*CAPK + s))*DD + t*4);
      acc.x = fmaf(g, (float)vb[0], acc.x); acc.y = fmaf(g, (float)vb[1], acc.y);
      acc.z = fmaf(g, (float)vb[2], acc.z); acc.w = fmaf(g, (float)vb[3], acc.w);
    }
  }
  *(float4*)(outp + (size_t)n*DD + t*4) = acc;
}

// ============================================================
extern "C" void kernel_launch(void* const* d_in, const int* in_sizes, int n_in,
                              void* d_out, int out_size, void* d_ws, size_t ws_size,
                              hipStream_t stream)
{
  const float* x    = (const float*)d_in[0];
  const float* ln1g = (const float*)d_in[1];
  const float* ln1b = (const float*)d_in[2];
  const float* Wq   = (const float*)d_in[3];
  const float* Wk   = (const float*)d_in[4];
  const float* Wv   = (const float*)d_in[5];
  const float* Wo   = (const float*)d_in[6];
  const float* bo   = (const float*)d_in[7];
  const float* ln2g = (const float*)d_in[8];
  const float* ln2b = (const float*)d_in[9];
  const float* Wg   = (const float*)d_in[10];
  const float* bg   = (const float*)d_in[11];
  const float* Wn   = (const float*)d_in[12];
  const float* bn   = (const float*)d_in[13];
  const float* W1   = (const float*)d_in[14];
  const float* b1   = (const float*)d_in[15];
  const float* W2   = (const float*)d_in[16];
  const float* b2   = (const float*)d_in[17];
  float* out = (float*)d_out;
  char* ws = (char*)d_ws;
  const size_t MB = 1u << 20;

  // workspace layout (time-aliased; peak ~145.5 MiB)
  __bf16* h1hi   = (__bf16*)(ws);             // 0..8   : LN1 hi (s1-3)
  __bf16* h1lo   = (__bf16*)(ws + 8*MB);      // 8..16  : LN1 lo
  __bf16* attnhi = (__bf16*)(ws);             // 0..8   : attn out hi (s4-5)
  __bf16* attnlo = (__bf16*)(ws + 8*MB);      // 8..16
  __bf16* h2b    = (__bf16*)(ws);             // 0..8   : LN2/h2 bf16 (s6-9)
  __bf16* Qhi    = (__bf16*)(ws + 16*MB);     // 16..24 (s3-4)
  __bf16* Qlo    = (__bf16*)(ws + 24*MB);     // 24..32
  __bf16* Khi    = (__bf16*)(ws + 32*MB);     // 32..40
  __bf16* Klo    = (__bf16*)(ws + 40*MB);     // 40..48
  __bf16* Vthi   = (__bf16*)(ws + 48*MB);     // 48..56
  __bf16* Vtlo   = (__bf16*)(ws + 56*MB);     // 56..64
  __bf16* W1T    = (__bf16*)(ws + 16*MB);     // 16..32 (s7-10; over Q, dead)
  __bf16* W2T    = (__bf16*)(ws + 32*MB);     // 32..48 (over K, dead)
  __bf16* xg     = (__bf16*)(ws + 48*MB);     // 48..64 (over V, dead)
  float*  x1     = (float*)(ws + 64*MB);      // 64..80 (s5-11)
  __bf16* eoutb  = (__bf16*)(ws + 80*MB);     // 80..96 (s10-11)
  __bf16* Bqh    = (__bf16*)(ws + 96*MB);     // 96..97.5 (s2-3)
  __bf16* Bql    = (__bf16*)(ws + 98*MB);     // 98..99.5
  __bf16* WoTh   = (__bf16*)(ws + 100*MB);    // 100..100.5 (s2-5)
  __bf16* WoTl   = (__bf16*)(ws + 101*MB);    // 101..101.5
  __bf16* mid    = (__bf16*)(ws + 112*MB);    // 112..144 (s10)
  char*   smallp = ws + 145*MB;
  int*   idx0     = (int*)smallp;
  int*   idx1     = idx0 + NTOK;
  float* g0       = (float*)(idx1 + NTOK);
  float* g1       = g0 + NTOK;
  int*   tok_slot = (int*)(g1 + NTOK);
  int*   idx_buf  = tok_slot + NTOK*2;

  // 1. LN1 -> hi/lo bf16
  ln_split<<<dim3(NTOK/4), dim3(64,4), 0, stream>>>(x, ln1g, ln1b, h1hi, h1lo);
  // 2. weight packing/transposes
  pack_qkv_split<<<dim3(8,24), 256, 0, stream>>>(Wq, Wk, Wv, Bqh, Bql);
  transp_split<<<dim3(8,8), 256, 0, stream>>>(Wo, WoTh, WoTl, DD, DD);
  // 3. QKV projection (bf16x3 MFMA) with fused split/transpose epilogue
  gemm_mfma3<1><<<dim3(12,64), 256, 0, stream>>>(h1hi, h1lo, Bqh, Bql,
      nullptr, nullptr, nullptr, Qhi, Qlo, Khi, Klo, Vthi, Vtlo, NTOK, 1536, DD);
  // 4. causal flash attention, bf16x3 MFMA, load-balanced pairing
  attn_mfma<<<dim3(32, 8), 512, 0, stream>>>(Qhi, Qlo, Khi, Klo, Vthi, Vtlo, attnhi, attnlo);
  // 5. Wo projection (bf16x3 MFMA) + bias + residual -> x1
  gemm_mfma3<0><<<dim3(4,64), 256, 0, stream>>>(attnhi, attnlo, WoTh, WoTl,
      bo, x, x1, nullptr, nullptr, nullptr, nullptr, nullptr, nullptr, NTOK, DD, DD);
  // 6. fused LN2 + router
  routerln_kernel<<<dim3(NTOK/4), 256, 0, stream>>>(x1, ln2g, ln2b, Wg, bg, Wn, bn,
      h2b, idx0, idx1, g0, g1);
  // 7. expert weights -> bf16 transposed
  transp_conv<<<dim3(32,8,NE), 256, 0, stream>>>(W1, W1T, DD, FF);
  transp_conv<<<dim3(8,32,NE), 256, 0, stream>>>(W2, W2T, FF, DD);
  // 8. capacity scan
  route_scan<<<dim3(NE), 256, 0, stream>>>(idx0, idx1, idx_buf, tok_slot);
  // 9. gather tokens per expert (bf16)
  gather_b<<<dim3(NE*CAPK), 128, 0, stream>>>(h2b, idx_buf, xg);
  // 10. expert FFN, 2 groups of 4 experts (mid reuse)
  for (int gg = 0; gg < 2; ++gg){
    gemm_mfma<1,1><<<dim3(FF/128, CAPK/128, 4), 256, 0, stream>>>(
        xg + (size_t)gg*4*CAPK*DD, W1T + (size_t)gg*4*DD*FF, b1 + (size_t)gg*4*FF,
        mid, CAPK, FF, DD);
    gemm_mfma<1,0><<<dim3(DD/128, CAPK/128, 4), 256, 0, stream>>>(
        mid, W2T + (size_t)gg*4*FF*DD, b2 + (size_t)gg*4*DD,
        eoutb + (size_t)gg*4*CAPK*DD, CAPK, DD, FF);
  }
  // 11. combine + residual
  combine_kernel<<<dim3(NTOK), 128, 0, stream>>>(x1, eoutb, idx0, idx1, g0, g1, tok_slot, out);
}

// Round 7
// 433.615 us; speedup vs baseline: 1.0424x; 1.0424x over previous
//
#include <hip/hip_runtime.h>
#include <math.h>

// ---------------- problem constants ----------------
#define TSEQ 2048
#define DD   512
#define NH   8
#define HSZ  64
#define NE   8
#define NTOK 8192    // B*T
#define CAPK 2048
#define FF   2048    // 4*D

typedef __bf16 bf16x8 __attribute__((ext_vector_type(8)));
typedef float  f32x4  __attribute__((ext_vector_type(4)));
typedef unsigned int u32;
typedef u32 u32x4 __attribute__((ext_vector_type(4)));

__device__ __forceinline__ void gload16(const void* g, void* l){
  __builtin_amdgcn_global_load_lds((const __attribute__((address_space(1))) u32*)g,
                                   (__attribute__((address_space(3))) u32*)l, 16, 0, 0);
}

__device__ __forceinline__ u32 pkbf(float a, float b){
  unsigned short ua = __builtin_bit_cast(unsigned short, (__bf16)a);
  unsigned short ub = __builtin_bit_cast(unsigned short, (__bf16)b);
  return (u32)ua | ((u32)ub << 16);
}

// ============================================================
// Threefry-2x32, key = (0, 42)
// ============================================================
__device__ __forceinline__ unsigned rotl32(unsigned x, int r){ return (x<<r)|(x>>(32-r)); }

__device__ __forceinline__ void threefry2x32(unsigned c0, unsigned c1, unsigned &o0, unsigned &o1){
  const unsigned k0 = 0u, k1 = 42u;
  const unsigned k2 = k0 ^ k1 ^ 0x1BD11BDAu;
  unsigned x0 = c0 + k0, x1 = c1 + k1;
#define TFR(rot) { x0 += x1; x1 = rotl32(x1, rot); x1 ^= x0; }
  TFR(13) TFR(15) TFR(26) TFR(6)   x0 += k1; x1 += k2 + 1u;
  TFR(17) TFR(29) TFR(16) TFR(24)  x0 += k2; x1 += k0 + 2u;
  TFR(13) TFR(15) TFR(26) TFR(6)   x0 += k0; x1 += k1 + 3u;
  TFR(17) TFR(29) TFR(16) TFR(24)  x0 += k1; x1 += k2 + 4u;
  TFR(13) TFR(15) TFR(26) TFR(6)   x0 += k2; x1 += k0 + 5u;
#undef TFR
  o0 = x0; o1 = x1;
}

__device__ __forceinline__ float erfinv_f(float x){
  float w = -log1pf(-x*x);
  float p;
  if (w < 5.0f){
    w -= 2.5f;
    p = 2.81022636e-08f;
    p = fmaf(p,w, 3.43273939e-07f);
    p = fmaf(p,w,-3.5233877e-06f);
    p = fmaf(p,w,-4.39150654e-06f);
    p = fmaf(p,w, 0.00021858087f);
    p = fmaf(p,w,-0.00125372503f);
    p = fmaf(p,w,-0.00417768164f);
    p = fmaf(p,w, 0.246640727f);
    p = fmaf(p,w, 1.50140941f);
  } else {
    w = sqrtf(w) - 3.0f;
    p = -0.000200214257f;
    p = fmaf(p,w, 0.000100950558f);
    p = fmaf(p,w, 0.00134934322f);
    p = fmaf(p,w,-0.00367342844f);
    p = fmaf(p,w, 0.00573950773f);
    p = fmaf(p,w,-0.0076224613f);
    p = fmaf(p,w, 0.00943887047f);
    p = fmaf(p,w, 1.00167406f);
    p = fmaf(p,w, 2.83297682f);
  }
  return p * x;
}

// ============================================================
// LayerNorm -> hi/lo bf16 (LN1)
// ============================================================
__global__ __launch_bounds__(256) void ln_split(const float* __restrict__ x,
    const float* __restrict__ gw, const float* __restrict__ bw,
    __bf16* __restrict__ ohi, __bf16* __restrict__ olo)
{
  int row  = blockIdx.x*4 + threadIdx.y;
  int lane = threadIdx.x;
  const float* xr = x + (size_t)row*DD;
  float4 a = *(const float4*)(xr + lane*4);
  float4 c = *(const float4*)(xr + 256 + lane*4);
  float s  = a.x+a.y+a.z+a.w + c.x+c.y+c.z+c.w;
  float ss = a.x*a.x+a.y*a.y+a.z*a.z+a.w*a.w + c.x*c.x+c.y*c.y+c.z*c.z+c.w*c.w;
  #pragma unroll
  for (int off = 32; off; off >>= 1){ s += __shfl_xor(s, off); ss += __shfl_xor(ss, off); }
  float m   = s * (1.0f/DD);
  float var = ss * (1.0f/DD) - m*m;
  float r   = 1.0f / sqrtf(var + 1e-5f);
  float4 g1 = *(const float4*)(gw + lane*4);
  float4 b1 = *(const float4*)(bw + lane*4);
  float4 g2 = *(const float4*)(gw + 256 + lane*4);
  float4 b2 = *(const float4*)(bw + 256 + lane*4);
  float f1[4], f2[4];
  f1[0]=(a.x-m)*r*g1.x+b1.x; f1[1]=(a.y-m)*r*g1.y+b1.y; f1[2]=(a.z-m)*r*g1.z+b1.z; f1[3]=(a.w-m)*r*g1.w+b1.w;
  f2[0]=(c.x-m)*r*g2.x+b2.x; f2[1]=(c.y-m)*r*g2.y+b2.y; f2[2]=(c.z-m)*r*g2.z+b2.z; f2[3]=(c.w-m)*r*g2.w+b2.w;
  __bf16 h1v[4] __attribute__((aligned(8))), l1v[4] __attribute__((aligned(8)));
  __bf16 h2v[4] __attribute__((aligned(8))), l2v[4] __attribute__((aligned(8)));
  #pragma unroll
  for (int j = 0; j < 4; ++j){
    __bf16 hb = (__bf16)f1[j]; h1v[j]=hb; l1v[j]=(__bf16)(f1[j]-(float)hb);
    __bf16 hc = (__bf16)f2[j]; h2v[j]=hc; l2v[j]=(__bf16)(f2[j]-(float)hc);
  }
  size_t base = (size_t)row*DD + lane*4;
  *(uint2*)(ohi + base)       = *(const uint2*)h1v;
  *(uint2*)(olo + base)       = *(const uint2*)l1v;
  *(uint2*)(ohi + base + 256) = *(const uint2*)h2v;
  *(uint2*)(olo + base + 256) = *(const uint2*)l2v;
}

// ============================================================
// Pack Wq|Wk|Wv (H,D,HS) -> transposed hi/lo bf16 [1536][512]
// ============================================================
__global__ __launch_bounds__(256) void pack_qkv_split(const float* __restrict__ Wq,
    const float* __restrict__ Wk, const float* __restrict__ Wv,
    __bf16* __restrict__ dhi, __bf16* __restrict__ dlo)
{
  __shared__ float t[64][65];
  int z = blockIdx.y;
  int kt = blockIdx.x*64;
  int sel = z >> 3, hh = z & 7;
  const float* W = (sel==0 ? Wq : (sel==1 ? Wk : Wv)) + (size_t)hh*DD*HSZ;
  int tid = threadIdx.x;
  int r = tid>>2, c0 = (tid&3)*16;
  #pragma unroll
  for (int j = 0; j < 16; j += 4){
    float4 v = *(const float4*)&W[(size_t)(kt+r)*HSZ + c0 + j];
    t[r][c0+j]=v.x; t[r][c0+j+1]=v.y; t[r][c0+j+2]=v.z; t[r][c0+j+3]=v.w;
  }
  __syncthreads();
  __bf16 hb[16] __attribute__((aligned(32)));
  __bf16 lb[16] __attribute__((aligned(32)));
  #pragma unroll
  for (int j = 0; j < 16; ++j){
    float f = t[c0+j][r];
    __bf16 h = (__bf16)f; hb[j]=h; lb[j]=(__bf16)(f-(float)h);
  }
  size_t off = (size_t)(z*64 + r)*512 + kt + c0;
  *(uint4*)(dhi+off) = ((const uint4*)hb)[0]; *(uint4*)(dhi+off+8) = ((const uint4*)hb)[1];
  *(uint4*)(dlo+off) = ((const uint4*)lb)[0]; *(uint4*)(dlo+off+8) = ((const uint4*)lb)[1];
}

// ============================================================
// Generic transpose + hi/lo split (Wo)
// ============================================================
__global__ __launch_bounds__(256) void transp_split(const float* __restrict__ src,
    __bf16* __restrict__ dhi, __bf16* __restrict__ dlo, int Ms, int Ns)
{
  __shared__ float t[64][65];
  int nt = blockIdx.x*64, mt = blockIdx.y*64;
  int tid = threadIdx.x;
  int r = tid>>2, c0 = (tid&3)*16;
  #pragma unroll
  for (int j = 0; j < 16; j += 4){
    float4 v = *(const float4*)&src[(size_t)(mt+r)*Ns + nt + c0 + j];
    t[r][c0+j]=v.x; t[r][c0+j+1]=v.y; t[r][c0+j+2]=v.z; t[r][c0+j+3]=v.w;
  }
  __syncthreads();
  __bf16 hb[16] __attribute__((aligned(32)));
  __bf16 lb[16] __attribute__((aligned(32)));
  #pragma unroll
  for (int j = 0; j < 16; ++j){
    float f = t[c0+j][r];
    __bf16 h = (__bf16)f; hb[j]=h; lb[j]=(__bf16)(f-(float)h);
  }
  size_t off = (size_t)(nt + r)*Ms + mt + c0;
  *(uint4*)(dhi+off) = ((const uint4*)hb)[0]; *(uint4*)(dhi+off+8) = ((const uint4*)hb)[1];
  *(uint4*)(dlo+off) = ((const uint4*)lb)[0]; *(uint4*)(dlo+off+8) = ((const uint4*)lb)[1];
}

// ============================================================
// bf16x3 split-precision MFMA GEMM, 2-phase double-buffered. (R4 proven)
// ============================================================
template<int BIAS, int RES>
__global__ __launch_bounds__(256) void gemm_mfma3(
    const __bf16* __restrict__ Ahi, const __bf16* __restrict__ Alo,
    const __bf16* __restrict__ Bhi, const __bf16* __restrict__ Blo,
    const float* __restrict__ bias, const float* __restrict__ res,
    float* __restrict__ C, int M, int N, int K)
{
  __shared__ __bf16 AsH[2][4096];
  __shared__ __bf16 AsL[2][4096];
  __shared__ __bf16 BsH[2][4096];
  __shared__ __bf16 BsL[2][4096];
  int m0 = blockIdx.y*128, n0 = blockIdx.x*128;
  int tid = threadIdx.x;
  int w = tid>>6, l = tid&63;
  int wm = w>>1, wn = w&1;
  int srow = w*32 + (l>>2);
  int skb  = (l&3)<<4;
  const char* agh = (const char*)(Ahi + (size_t)(m0+srow)*K) + skb;
  const char* agl = (const char*)(Alo + (size_t)(m0+srow)*K) + skb;
  const char* bgh = (const char*)(Bhi + (size_t)(n0+srow)*K) + skb;
  const char* bgl = (const char*)(Blo + (size_t)(n0+srow)*K) + skb;
  size_t r16 = (size_t)16*K*sizeof(__bf16);

  f32x4 acc[4][4] = {};
  int rl = l & 15, kh = l >> 4;
  const __bf16* abh = &AsH[0][(wm*64 + rl)*32 + kh*8];
  const __bf16* abl = &AsL[0][(wm*64 + rl)*32 + kh*8];
  const __bf16* bbh = &BsH[0][(wn*64 + rl)*32 + kh*8];
  const __bf16* bbl = &BsL[0][(wn*64 + rl)*32 + kh*8];

  auto STAGE = [&](int bb, int kt){
    size_t o = (size_t)kt*64;
    gload16(agh+o,     &AsH[bb][w*1024]);
    gload16(agh+o+r16, &AsH[bb][w*1024+512]);
    gload16(agl+o,     &AsL[bb][w*1024]);
    gload16(agl+o+r16, &AsL[bb][w*1024+512]);
    gload16(bgh+o,     &BsH[bb][w*1024]);
    gload16(bgh+o+r16, &BsH[bb][w*1024+512]);
    gload16(bgl+o,     &BsL[bb][w*1024]);
    gload16(bgl+o+r16, &BsL[bb][w*1024+512]);
  };

  int nkt = K >> 5;
  STAGE(0, 0);
  __syncthreads();
  for (int kt = 0; kt < nkt; ++kt){
    int bb = kt & 1;
    if (kt + 1 < nkt) STAGE(bb^1, kt+1);
    bf16x8 afh[4], afl[4], bfh[4], bfl[4];
    #pragma unroll
    for (int i = 0; i < 4; ++i){
      afh[i] = *(const bf16x8*)(abh + bb*4096 + i*512);
      afl[i] = *(const bf16x8*)(abl + bb*4096 + i*512);
      bfh[i] = *(const bf16x8*)(bbh + bb*4096 + i*512);
      bfl[i] = *(const bf16x8*)(bbl + bb*4096 + i*512);
    }
    #pragma unroll
    for (int fm = 0; fm < 4; ++fm)
      #pragma unroll
      for (int fn = 0; fn < 4; ++fn){
        acc[fm][fn] = __builtin_amdgcn_mfma_f32_16x16x32_bf16(afh[fm], bfl[fn], acc[fm][fn], 0, 0, 0);
        acc[fm][fn] = __builtin_amdgcn_mfma_f32_16x16x32_bf16(afl[fm], bfh[fn], acc[fm][fn], 0, 0, 0);
        acc[fm][fn] = __builtin_amdgcn_mfma_f32_16x16x32_bf16(afh[fm], bfh[fn], acc[fm][fn], 0, 0, 0);
      }
    __syncthreads();
  }

  int ccol = l & 15, cr = (l >> 4) * 4;
  #pragma unroll
  for (int fn = 0; fn < 4; ++fn){
    int n = n0 + wn*64 + fn*16 + ccol;
    float bv = BIAS ? bias[n] : 0.0f;
    #pragma unroll
    for (int fm = 0; fm < 4; ++fm){
      int mb = m0 + wm*64 + fm*16 + cr;
      #pragma unroll
      for (int r = 0; r < 4; ++r){
        float v = acc[fm][fn][r] + bv;
        if (RES) v += res[(size_t)(mb+r)*N + n];
        C[(size_t)(mb+r)*N + n] = v;
      }
    }
  }
}

// ============================================================
// bf16 MFMA GEMM (experts), 2-phase double-buffered, 1-D grid with
// expert = flat&3 (XCD locality), optional gather-indirect A staging.
// grid = 4 experts * (M/128 * 2^LOGN) blocks.
// ============================================================
template<int STORE_BF16, int RELU, int GATHER, int LOGN>
__global__ __launch_bounds__(256) void gemm_mfma(
    const __bf16* __restrict__ A, const __bf16* __restrict__ Bt,
    const float* __restrict__ bias, void* __restrict__ Cv,
    const int* __restrict__ idxb, int M, int N, int K)
{
  __shared__ __bf16 Asl[2][4096];
  __shared__ __bf16 Bsl[2][4096];
  int flat = blockIdx.x;
  int e = flat & 3;
  int tile = flat >> 2;
  int n0 = (tile & ((1<<LOGN)-1)) * 128;
  int m0 = (tile >> LOGN) * 128;
  const __bf16* Be = Bt + (size_t)e*N*K;
  const float*  be = bias + (size_t)e*N;
  int tid = threadIdx.x;
  int w = tid>>6, l = tid&63;
  int wm = w>>1, wn = w&1;
  int srow = w*32 + (l>>2);
  int skb  = (l&3)<<4;
  const char* ag;
  if (GATHER){
    int tok = idxb[e*CAPK + m0 + srow];
    ag = (const char*)(A + (size_t)tok*K) + skb;
  } else {
    ag = (const char*)(A + (size_t)e*M*K + (size_t)(m0 + srow)*K) + skb;
  }
  const char* bg = (const char*)(Be + (size_t)(n0 + srow)*K) + skb;
  size_t r16;
  if (GATHER){
    // row srow+16's token differs; precompute second-row pointer instead of stride
    int tok2 = idxb[e*CAPK + m0 + srow + 16];
    r16 = (size_t)((const char*)(A + (size_t)tok2*K) + skb - ag);
  } else {
    r16 = (size_t)16*K*sizeof(__bf16);
  }

  f32x4 acc[4][4] = {};
  int rl = l & 15, kh = l >> 4;
  const __bf16* abase = &Asl[0][(wm*64 + rl)*32 + kh*8];
  const __bf16* bbase = &Bsl[0][(wn*64 + rl)*32 + kh*8];

  size_t br16 = (size_t)16*K*sizeof(__bf16);
  auto STAGE = [&](int bb, int kt){
    size_t o = (size_t)kt*64;
    gload16(ag+o,      &Asl[bb][w*1024]);
    gload16(ag+o+r16,  &Asl[bb][w*1024+512]);
    gload16(bg+o,      &Bsl[bb][w*1024]);
    gload16(bg+o+br16, &Bsl[bb][w*1024+512]);
  };

  int nkt = K >> 5;
  STAGE(0, 0);
  __syncthreads();
  for (int kt = 0; kt < nkt; ++kt){
    int bb = kt & 1;
    if (kt + 1 < nkt) STAGE(bb^1, kt+1);
    bf16x8 af[4], bf[4];
    #pragma unroll
    for (int i = 0; i < 4; ++i){
      af[i] = *(const bf16x8*)(abase + bb*4096 + i*512);
      bf[i] = *(const bf16x8*)(bbase + bb*4096 + i*512);
    }
    #pragma unroll
    for (int fm = 0; fm < 4; ++fm)
      #pragma unroll
      for (int fn = 0; fn < 4; ++fn)
        acc[fm][fn] = __builtin_amdgcn_mfma_f32_16x16x32_bf16(af[fm], bf[fn], acc[fm][fn], 0, 0, 0);
    __syncthreads();
  }

  int ccol = l & 15, cr = (l >> 4) * 4;
  char* Ce = (char*)Cv + (size_t)e*M*N*(STORE_BF16 ? 2 : 4);
  #pragma unroll
  for (int fn = 0; fn < 4; ++fn){
    int n = n0 + wn*64 + fn*16 + ccol;
    float bv = be[n];
    #pragma unroll
    for (int fm = 0; fm < 4; ++fm){
      int mb = m0 + wm*64 + fm*16 + cr;
      #pragma unroll
      for (int r = 0; r < 4; ++r){
        float v = acc[fm][fn][r] + bv;
        if (RELU) v = fmaxf(v, 0.f);
        if (STORE_BF16) ((__bf16*)Ce)[(size_t)(mb+r)*N + n] = (__bf16)v;
        else            ((float*)Ce)[(size_t)(mb+r)*N + n] = v;
      }
    }
  }
}

// ============================================================
// Transpose + convert expert weights (f32 -> plain bf16 [N][K])
// ============================================================
__global__ __launch_bounds__(256) void transp_conv(const float* __restrict__ src,
    __bf16* __restrict__ dst, int Ms, int Ns)
{
  __shared__ __bf16 t[64][72];
  int e = blockIdx.z;
  const float* s = src + (size_t)e*Ms*Ns;
  __bf16* d = dst + (size_t)e*Ms*Ns;
  int mt = blockIdx.y*64, nt = blockIdx.x*64;
  int tid = threadIdx.x;
  int r = tid>>2, c0 = (tid&3)*16;
  #pragma unroll
  for (int j = 0; j < 16; j += 4){
    float4 v = *(const float4*)&s[(size_t)(mt+r)*Ns + nt + c0 + j];
    t[r][c0+j]   = (__bf16)v.x; t[r][c0+j+1] = (__bf16)v.y;
    t[r][c0+j+2] = (__bf16)v.z; t[r][c0+j+3] = (__bf16)v.w;
  }
  __syncthreads();
  __bf16 tmp[16] __attribute__((aligned(32)));
  #pragma unroll
  for (int j = 0; j < 16; ++j) tmp[j] = t[c0+j][r];
  uint4* dp = (uint4*)&d[(size_t)(nt+r)*Ms + mt + c0];
  dp[0] = ((const uint4*)tmp)[0];
  dp[1] = ((const uint4*)tmp)[1];
}

// ============================================================
// Convert K,V (f32 in qkv) to hi/lo bf16; V transposed. (R4 proven)
// ============================================================
__global__ __launch_bounds__(256) void convert_kv(const float* __restrict__ qkv,
    __bf16* __restrict__ khi, __bf16* __restrict__ klo,
    __bf16* __restrict__ vthi, __bf16* __restrict__ vtlo)
{
  int t0 = blockIdx.x*64;
  int bh = blockIdx.y;
  int b = bh >> 3, h = bh & 7;
  int tid = threadIdx.x;
  {
    int r = tid >> 2, e0 = (tid & 3) * 16;
    const float* src = qkv + ((size_t)(b*TSEQ + t0 + r))*1536 + 512 + h*64 + e0;
    __bf16 hi[16] __attribute__((aligned(16)));
    __bf16 lo[16] __attribute__((aligned(16)));
    #pragma unroll
    for (int j = 0; j < 16; j += 4){
      float4 v = *(const float4*)(src + j);
      float f[4] = {v.x, v.y, v.z, v.w};
      #pragma unroll
      for (int q = 0; q < 4; ++q){
        __bf16 hb = (__bf16)f[q];
        hi[j+q] = hb; lo[j+q] = (__bf16)(f[q] - (float)hb);
      }
    }
    size_t off = ((size_t)(bh*TSEQ + t0 + r))*64 + e0;
    *(uint4*)(khi + off)     = ((const uint4*)hi)[0];
    *(uint4*)(khi + off + 8) = ((const uint4*)hi)[1];
    *(uint4*)(klo + off)     = ((const uint4*)lo)[0];
    *(uint4*)(klo + off + 8) = ((const uint4*)lo)[1];
  }
  {
    int key0 = (tid & 15) * 4, e0 = (tid >> 4) * 4;
    float4 v[4];
    #pragma unroll
    for (int j = 0; j < 4; ++j)
      v[j] = *(const float4*)(qkv + ((size_t)(b*TSEQ + t0 + key0 + j))*1536 + 1024 + h*64 + e0);
    float col[4][4];
    col[0][0]=v[0].x; col[0][1]=v[1].x; col[0][2]=v[2].x; col[0][3]=v[3].x;
    col[1][0]=v[0].y; col[1][1]=v[1].y; col[1][2]=v[2].y; col[1][3]=v[3].y;
    col[2][0]=v[0].z; col[2][1]=v[1].z; col[2][2]=v[2].z; col[2][3]=v[3].z;
    col[3][0]=v[0].w; col[3][1]=v[1].w; col[3][2]=v[2].w; col[3][3]=v[3].w;
    #pragma unroll
    for (int kk = 0; kk < 4; ++kk){
      __bf16 hi[4] __attribute__((aligned(8)));
      __bf16 lo[4] __attribute__((aligned(8)));
      #pragma unroll
      for (int j = 0; j < 4; ++j){
        __bf16 hb = (__bf16)col[kk][j];
        hi[j] = hb; lo[j] = (__bf16)(col[kk][j] - (float)hb);
      }
      size_t off = ((size_t)(bh*64 + e0 + kk))*TSEQ + t0 + key0;
      *(uint2*)(vthi + off) = *(const uint2*)hi;
      *(uint2*)(vtlo + off) = *(const uint2*)lo;
    }
  }
}

// ============================================================
// bf16x3 MFMA flash attention (R4 proven: exp2, defer-max, pairing, no setprio)
// ============================================================
__global__ __launch_bounds__(512) void attn_mfma(const float* __restrict__ qkv,
    const __bf16* __restrict__ khi_g, const __bf16* __restrict__ klo_g,
    const __bf16* __restrict__ vthi_g, const __bf16* __restrict__ vtlo_g,
    __bf16* __restrict__ ahi, __bf16* __restrict__ alo)
{
  __shared__ __align__(16) char ldsbuf[65536];   // [2 buf][4 arr][8KB]
  int bh = blockIdx.x;
  int qtA = blockIdx.y, qtB = 15 - qtA;
  int b = bh >> 3, h = bh & 7;
  int tid = threadIdx.x;
  int w = tid >> 6, l = tid & 63;
  int g = l >> 4, r = l & 15;
  int sA = r + 32*(g & 1);
  int sB = sA + 16;
  int ghalf = g >> 1;
  const float qsc = 0.04419417382415922f * 1.4426950408889634f;  // D^-0.5 * log2(e)

  int qb[2]; qb[0] = qtA*128 + w*16; qb[1] = qtB*128 + (7-w)*16;
  int kdiag[2]; kdiag[0] = qb[0] >> 6; kdiag[1] = qb[1] >> 6;

  bf16x8 qhi[2][2], qlo[2][2];
  #pragma unroll
  for (int qf = 0; qf < 2; ++qf)
    #pragma unroll
    for (int ks = 0; ks < 2; ++ks){
      const float* src = qkv + ((size_t)(b*TSEQ + qb[qf] + r))*1536 + h*64 + ks*32 + g*8;
      float4 v0 = *(const float4*)src;
      float4 v1 = *(const float4*)(src + 4);
      float f[8] = {v0.x,v0.y,v0.z,v0.w,v1.x,v1.y,v1.z,v1.w};
      bf16x8 hi, lo;
      #pragma unroll
      for (int i = 0; i < 8; ++i){
        float fs = f[i] * qsc;
        __bf16 hb = (__bf16)fs;
        hi[i] = hb; lo[i] = (__bf16)(fs - (float)hb);
      }
      qhi[qf][ks] = hi; qlo[qf][ks] = lo;
    }

  f32x4 ot[4][2] = {};
  float m_r[2] = {-INFINITY, -INFINITY};
  float l_r[2] = {0.f, 0.f};

  int nkt = 2*qtB + 2;
  size_t kbase = (size_t)bh*TSEQ*64;
  size_t vbase = (size_t)bh*64*TSEQ;

  auto STAGE = [&](int buf, int kt){
    int row = tid >> 3, cc = tid & 7;
    int sw = (cc ^ (row & 7)) * 8;
    char* d = ldsbuf + buf*32768 + (w << 10);
    gload16(khi_g  + kbase + (size_t)(kt*64 + row)*64 + sw, d);
    gload16(klo_g  + kbase + (size_t)(kt*64 + row)*64 + sw, d + 8192);
    gload16(vthi_g + vbase + (size_t)row*TSEQ + kt*64 + sw,  d + 16384);
    gload16(vtlo_g + vbase + (size_t)row*TSEQ + kt*64 + sw,  d + 24576);
  };

  STAGE(0, 0);
  __syncthreads();

  for (int kt = 0; kt < nkt; ++kt){
    int buf = kt & 1;
    if (kt + 1 < nkt) STAGE(buf ^ 1, kt + 1);

    bool act[2];
    act[0] = (kt <= kdiag[0]);
    act[1] = (kt <= kdiag[1]);

    const char* K0 = ldsbuf + buf*32768;
    const char* K1 = K0 + 8192;
    const char* V0 = K0 + 16384;
    const char* V1 = K0 + 24576;

    f32x4 s[4][2] = {};
    #pragma unroll
    for (int kf = 0; kf < 4; ++kf){
      int rowk = kf*16 + r;
      int rsw = (rowk & 7) << 4;
      #pragma unroll
      for (int ks = 0; ks < 2; ++ks){
        int off = rowk*128 + ((((ks*4 + g) << 4)) ^ rsw);
        bf16x8 khf = *(const bf16x8*)(K0 + off);
        bf16x8 klf = *(const bf16x8*)(K1 + off);
        #pragma unroll
        for (int qf = 0; qf < 2; ++qf){
          if (act[qf]){
            s[kf][qf] = __builtin_amdgcn_mfma_f32_16x16x32_bf16(khf, qlo[qf][ks], s[kf][qf], 0,0,0);
            s[kf][qf] = __builtin_amdgcn_mfma_f32_16x16x32_bf16(klf, qhi[qf][ks], s[kf][qf], 0,0,0);
            s[kf][qf] = __builtin_amdgcn_mfma_f32_16x16x32_bf16(khf, qhi[qf][ks], s[kf][qf], 0,0,0);
          }
        }
      }
    }

    u32 phi[4][2][2], plo[4][2][2];
    #pragma unroll
    for (int qf = 0; qf < 2; ++qf){
      if (act[qf]){
        int q = qb[qf] + r;
        float p[4][4];
        float mx = -INFINITY;
        if (kt == kdiag[qf]){
          #pragma unroll
          for (int kf = 0; kf < 4; ++kf)
            #pragma unroll
            for (int e = 0; e < 4; ++e){
              int key = kt*64 + kf*16 + g*4 + e;
              float sv = (key <= q) ? s[kf][qf][e] : -INFINITY;
              p[kf][e] = sv;
              mx = fmaxf(mx, sv);
            }
        } else {
          #pragma unroll
          for (int kf = 0; kf < 4; ++kf)
            #pragma unroll
            for (int e = 0; e < 4; ++e){
              float sv = s[kf][qf][e];
              p[kf][e] = sv;
              mx = fmaxf(mx, sv);
            }
        }
        mx = fmaxf(mx, __shfl_xor(mx, 16));
        mx = fmaxf(mx, __shfl_xor(mx, 32));
        if (__any(mx > m_r[qf])){
          float mn = fmaxf(m_r[qf], mx);
          float fj = exp2f(m_r[qf] - mn);
          m_r[qf] = mn;
          l_r[qf] *= fj;
          #pragma unroll
          for (int ef = 0; ef < 4; ++ef)
            #pragma unroll
            for (int e = 0; e < 4; ++e)
              ot[ef][qf][e] *= fj;
        }
        float ts = 0.f;
        #pragma unroll
        for (int kf = 0; kf < 4; ++kf)
          #pragma unroll
          for (int e = 0; e < 4; ++e){
            float pv = exp2f(p[kf][e] - m_r[qf]);
            p[kf][e] = pv; ts += pv;
          }
        ts += __shfl_xor(ts, 16); ts += __shfl_xor(ts, 32);
        l_r[qf] += ts;
        #pragma unroll
        for (int kf = 0; kf < 4; ++kf){
          __bf16 h0=(__bf16)p[kf][0], h1=(__bf16)p[kf][1], h2=(__bf16)p[kf][2], h3=(__bf16)p[kf][3];
          phi[kf][qf][0] = pkbf(p[kf][0], p[kf][1]);
          phi[kf][qf][1] = pkbf(p[kf][2], p[kf][3]);
          plo[kf][qf][0] = pkbf(p[kf][0]-(float)h0, p[kf][1]-(float)h1);
          plo[kf][qf][1] = pkbf(p[kf][2]-(float)h2, p[kf][3]-(float)h3);
        }
      }
    }

    #pragma unroll
    for (int ks = 0; ks < 2; ++ks){
      u32x4 pbh[2], pbl[2];
      #pragma unroll
      for (int qf = 0; qf < 2; ++qf){
        if (act[qf]){
          #pragma unroll
          for (int p2 = 0; p2 < 2; ++p2){
            u32 hA0 = (u32)__shfl((int)phi[2*ks  ][qf][p2], sA);
            u32 hA1 = (u32)__shfl((int)phi[2*ks+1][qf][p2], sA);
            u32 hB0 = (u32)__shfl((int)phi[2*ks  ][qf][p2], sB);
            u32 hB1 = (u32)__shfl((int)phi[2*ks+1][qf][p2], sB);
            pbh[qf][p2]   = ghalf ? hA1 : hA0;
            pbh[qf][2+p2] = ghalf ? hB1 : hB0;
            u32 lA0 = (u32)__shfl((int)plo[2*ks  ][qf][p2], sA);
            u32 lA1 = (u32)__shfl((int)plo[2*ks+1][qf][p2], sA);
            u32 lB0 = (u32)__shfl((int)plo[2*ks  ][qf][p2], sB);
            u32 lB1 = (u32)__shfl((int)plo[2*ks+1][qf][p2], sB);
            pbl[qf][p2]   = ghalf ? lA1 : lA0;
            pbl[qf][2+p2] = ghalf ? lB1 : lB0;
          }
        }
      }
      #pragma unroll
      for (int ef = 0; ef < 4; ++ef){
        int rowv = ef*16 + r;
        int off = rowv*128 + ((((ks*4 + g) << 4)) ^ ((rowv & 7) << 4));
        bf16x8 vhf = *(const bf16x8*)(V0 + off);
        bf16x8 vlf = *(const bf16x8*)(V1 + off);
        #pragma unroll
        for (int qf = 0; qf < 2; ++qf){
          if (act[qf]){
            bf16x8 ph = __builtin_bit_cast(bf16x8, pbh[qf]);
            bf16x8 pl = __builtin_bit_cast(bf16x8, pbl[qf]);
            ot[ef][qf] = __builtin_amdgcn_mfma_f32_16x16x32_bf16(vhf, pl, ot[ef][qf], 0,0,0);
            ot[ef][qf] = __builtin_amdgcn_mfma_f32_16x16x32_bf16(vlf, ph, ot[ef][qf], 0,0,0);
            ot[ef][qf] = __builtin_amdgcn_mfma_f32_16x16x32_bf16(vhf, ph, ot[ef][qf], 0,0,0);
          }
        }
      }
    }
    __syncthreads();
  }

  float* Osh = (float*)ldsbuf;   // [128][68]
  #pragma unroll
  for (int qf = 0; qf < 2; ++qf){
    float inv = 1.0f / l_r[qf];
    int qloc = (qf ? (7-w) : w)*16 + r;
    #pragma unroll
    for (int ef = 0; ef < 4; ++ef)
      #pragma unroll
      for (int e = 0; e < 4; ++e)
        Osh[qloc*68 + ef*16 + g*4 + e] = ot[ef][qf][e] * inv;
    __syncthreads();
    {
      int qt = qf ? qtB : qtA;
      int q = tid >> 2, e0 = (tid & 3)*16;
      const float* srow = Osh + q*68 + e0;
      size_t base = ((size_t)(b*TSEQ + qt*128 + q))*DD + h*64 + e0;
      #pragma unroll
      for (int j = 0; j < 4; ++j){
        float4 v = *(const float4*)(srow + j*4);
        float f[4] = {v.x, v.y, v.z, v.w};
        __bf16 hb[4] __attribute__((aligned(8)));
        __bf16 lb[4] __attribute__((aligned(8)));
        #pragma unroll
        for (int q2 = 0; q2 < 4; ++q2){
          __bf16 h2b = (__bf16)f[q2];
          hb[q2] = h2b; lb[q2] = (__bf16)(f[q2] - (float)h2b);
        }
        *(uint2*)(ahi + base + j*4) = *(const uint2*)hb;
        *(uint2*)(alo + base + j*4) = *(const uint2*)lb;
      }
    }
    __syncthreads();
  }
}

// ============================================================
// Fused LN2 + Router: reads x1, writes h2 (bf16) + routing
// ============================================================
__global__ __launch_bounds__(256) void routerln_kernel(const float* __restrict__ x1,
    const float* __restrict__ gw, const float* __restrict__ bw,
    const float* __restrict__ Wg, const float* __restrict__ bg,
    const float* __restrict__ Wn, const float* __restrict__ bn,
    __bf16* __restrict__ h2b,
    int* __restrict__ idx0, int* __restrict__ idx1,
    float* __restrict__ g0, float* __restrict__ g1)
{
  int wid = threadIdx.x >> 6, lane = threadIdx.x & 63;
  int tok = blockIdx.x*4 + wid;
  const float* xr = x1 + (size_t)tok*DD;
  float4 a = *(const float4*)(xr + lane*4);
  float4 c = *(const float4*)(xr + 256 + lane*4);
  float s  = a.x+a.y+a.z+a.w + c.x+c.y+c.z+c.w;
  float ss = a.x*a.x+a.y*a.y+a.z*a.z+a.w*a.w + c.x*c.x+c.y*c.y+c.z*c.z+c.w*c.w;
  #pragma unroll
  for (int off = 32; off; off >>= 1){ s += __shfl_xor(s, off); ss += __shfl_xor(ss, off); }
  float m   = s * (1.0f/DD);
  float var = ss * (1.0f/DD) - m*m;
  float rr  = 1.0f / sqrtf(var + 1e-5f);
  float4 g1v = *(const float4*)(gw + lane*4);
  float4 b1v = *(const float4*)(bw + lane*4);
  float4 g2v = *(const float4*)(gw + 256 + lane*4);
  float4 b2v = *(const float4*)(bw + 256 + lane*4);
  float f1[4], f2[4];
  f1[0]=(a.x-m)*rr*g1v.x+b1v.x; f1[1]=(a.y-m)*rr*g1v.y+b1v.y; f1[2]=(a.z-m)*rr*g1v.z+b1v.z; f1[3]=(a.w-m)*rr*g1v.w+b1v.w;
  f2[0]=(c.x-m)*rr*g2v.x+b2v.x; f2[1]=(c.y-m)*rr*g2v.y+b2v.y; f2[2]=(c.z-m)*rr*g2v.z+b2v.z; f2[3]=(c.w-m)*rr*g2v.w+b2v.w;
  {
    __bf16 h1v[4] __attribute__((aligned(8)));
    __bf16 h2v[4] __attribute__((aligned(8)));
    #pragma unroll
    for (int j = 0; j < 4; ++j){ h1v[j] = (__bf16)f1[j]; h2v[j] = (__bf16)f2[j]; }
    size_t base = (size_t)tok*DD + lane*4;
    *(uint2*)(h2b + base)       = *(const uint2*)h1v;
    *(uint2*)(h2b + base + 256) = *(const uint2*)h2v;
  }
  float ag[8] = {0,0,0,0,0,0,0,0}, an[8] = {0,0,0,0,0,0,0,0};
  int d1 = lane*4, d2 = 256 + lane*4;
  #pragma unroll
  for (int j = 0; j < 4; ++j){
    const float* wg1 = Wg + (size_t)(d1+j)*8;
    const float* wn1 = Wn + (size_t)(d1+j)*8;
    const float* wg2 = Wg + (size_t)(d2+j)*8;
    const float* wn2 = Wn + (size_t)(d2+j)*8;
    #pragma unroll
    for (int e = 0; e < 8; ++e){
      ag[e] = fmaf(f1[j], wg1[e], ag[e]); an[e] = fmaf(f1[j], wn1[e], an[e]);
      ag[e] = fmaf(f2[j], wg2[e], ag[e]); an[e] = fmaf(f2[j], wn2[e], an[e]);
    }
  }
  #pragma unroll
  for (int off = 32; off; off >>= 1){
    #pragma unroll
    for (int e = 0; e < 8; ++e){ ag[e] += __shfl_xor(ag[e], off); an[e] += __shfl_xor(an[e], off); }
  }
  __shared__ float ns[4][8];
  if (lane < 8){
    int e = lane;
    float lg = ag[e] + bg[e];
    float nl = an[e] + bn[e];
    float sp = fmaxf(nl, 0.f) + log1pf(expf(-fabsf(nl)));
    unsigned i = (unsigned)(tok*8 + e);
    unsigned r0b, r1b;
    threefry2x32(0u, i, r0b, r1b);
    unsigned bits = r0b ^ r1b;
    float f = __uint_as_float((bits >> 9) | 0x3f800000u) - 1.0f;
    float u = fmaf(f, 2.0f, -0.99999994f);
    u = fmaxf(u, -0.99999994f);
    float z = 1.41421356f * erfinv_f(u);
    ns[wid][e] = lg + z*sp;
  }
  __syncthreads();
  if (lane == 0){
    float v0 = -INFINITY; int i0 = 0;
    #pragma unroll
    for (int e = 0; e < 8; ++e){ float v = ns[wid][e]; if (v > v0){ v0 = v; i0 = e; } }
    float v1 = -INFINITY; int i1 = 0;
    #pragma unroll
    for (int e = 0; e < 8; ++e){ if (e != i0){ float v = ns[wid][e]; if (v > v1){ v1 = v; i1 = e; } } }
    float dexp = expf(v1 - v0);
    float ssum = 1.0f + dexp;
    idx0[tok] = i0; idx1[tok] = i1;
    g0[tok] = 1.0f/ssum; g1[tok] = dexp/ssum;
  }
}

// ============================================================
// Capacity routing
// ============================================================
__global__ __launch_bounds__(256) void route_scan(const int* __restrict__ idx0,
    const int* __restrict__ idx1, int* __restrict__ idx_buf, int* __restrict__ tok_slot)
{
  int e = blockIdx.x, tid = threadIdx.x;
  for (int i = tid; i < CAPK; i += 256) idx_buf[e*CAPK + i] = 0;
  __syncthreads();
  int base = tid * 32;
  int cnt = 0;
  for (int j = 0; j < 32; ++j){ int t = base + j; cnt += (idx0[t]==e || idx1[t]==e) ? 1 : 0; }
  __shared__ int ps[256];
  ps[tid] = cnt; __syncthreads();
  for (int off = 1; off < 256; off <<= 1){
    int add = (tid >= off) ? ps[tid - off] : 0;
    __syncthreads();
    ps[tid] += add;
    __syncthreads();
  }
  int slot = ps[tid] - cnt;
  for (int j = 0; j < 32; ++j){
    int t = base + j;
    int k = (idx0[t]==e) ? 0 : ((idx1[t]==e) ? 1 : -1);
    if (k >= 0){
      if (slot < CAPK){ idx_buf[e*CAPK + slot] = t; tok_slot[t*2 + k] = slot; }
      else            { tok_slot[t*2 + k] = -1; }
      slot++;
    }
  }
}

// ============================================================
// Combine (eout bf16)
// ============================================================
__global__ __launch_bounds__(128) void combine_kernel(const float* __restrict__ x1,
    const __bf16* __restrict__ eout, const int* __restrict__ idx0, const int* __restrict__ idx1,
    const float* __restrict__ g0, const float* __restrict__ g1,
    const int* __restrict__ tok_slot, float* __restrict__ outp)
{
  int n = blockIdx.x, t = threadIdx.x;
  float4 acc = *(const float4*)(x1 + (size_t)n*DD + t*4);
  #pragma unroll
  for (int k = 0; k < 2; ++k){
    int s = tok_slot[n*2 + k];
    if (s >= 0){
      int e  = (k==0) ? idx0[n] : idx1[n];
      float g = (k==0) ? g0[n] : g1[n];
      __bf16 vb[4] __attribute__((aligned(8)));
      *(uint2*)vb = *(const uint2*)(eout + ((size_t)(e*CAPK + s))*DD + t*4);
      acc.x = fmaf(g, (float)vb[0], acc.x); acc.y = fmaf(g, (float)vb[1], acc.y);
      acc.z = fmaf(g, (float)vb[2], acc.z); acc.w = fmaf(g, (float)vb[3], acc.w);
    }
  }
  *(float4*)(outp + (size_t)n*DD + t*4) = acc;
}

// ============================================================
extern "C" void kernel_launch(void* const* d_in, const int* in_sizes, int n_in,
                              void* d_out, int out_size, void* d_ws, size_t ws_size,
                              hipStream_t stream)
{
  const float* x    = (const float*)d_in[0];
  const float* ln1g = (const float*)d_in[1];
  const float* ln1b = (const float*)d_in[2];
  const float* Wq   = (const float*)d_in[3];
  const float* Wk   = (const float*)d_in[4];
  const float* Wv   = (const float*)d_in[5];
  const float* Wo   = (const float*)d_in[6];
  const float* bo   = (const float*)d_in[7];
  const float* ln2g = (const float*)d_in[8];
  const float* ln2b = (const float*)d_in[9];
  const float* Wg   = (const float*)d_in[10];
  const float* bg   = (const float*)d_in[11];
  const float* Wn   = (const float*)d_in[12];
  const float* bn   = (const float*)d_in[13];
  const float* W1   = (const float*)d_in[14];
  const float* b1   = (const float*)d_in[15];
  const float* W2   = (const float*)d_in[16];
  const float* b2   = (const float*)d_in[17];
  float* out = (float*)d_out;
  char* ws = (char*)d_ws;
  const size_t MB = 1u << 20;

  // workspace layout (time-aliased; peak ~145.5 MiB)
  __bf16* h1hi   = (__bf16*)(ws);             // 0..8   : LN1 hi (s1-3)
  __bf16* h1lo   = (__bf16*)(ws + 8*MB);      // 8..16  : LN1 lo
  __bf16* attnhi = (__bf16*)(ws);             // 0..8   : attn out hi (s4b-5)
  __bf16* attnlo = (__bf16*)(ws + 8*MB);      // 8..16
  __bf16* h2b    = (__bf16*)(ws);             // 0..8   : LN2 out bf16 (s6-10)
  float*  qkv    = (float*)(ws + 16*MB);      // 16..64 : qkv f32 (s3-4b)
  __bf16* W1T    = (__bf16*)(ws + 16*MB);     // 16..32 : (s7-10)
  __bf16* W2T    = (__bf16*)(ws + 32*MB);     // 32..48 : (s7-10)
  float*  x1     = (float*)(ws + 64*MB);      // 64..80 : (s5-11)
  __bf16* Khi    = (__bf16*)(ws + 80*MB);     // 80..88 : (s4a-4b)
  __bf16* Klo    = (__bf16*)(ws + 88*MB);     // 88..96
  __bf16* Vthi   = (__bf16*)(ws + 96*MB);     // 96..104
  __bf16* Vtlo   = (__bf16*)(ws + 104*MB);    // 104..112
  __bf16* Bqh    = (__bf16*)(ws + 80*MB);     // 80..81.5 : qkv W hi (s2-3; dead before s4a)
  __bf16* Bql    = (__bf16*)(ws + 82*MB);     // 82..83.5
  __bf16* eoutb  = (__bf16*)(ws + 80*MB);     // 80..96 : expert out bf16 (s10-11)
  __bf16* mid    = (__bf16*)(ws + 112*MB);    // 112..144 : per-group mid (s10)
  __bf16* WoTh   = (__bf16*)(ws + 144*MB);    // 144..144.5 (s2-5)
  __bf16* WoTl   = (__bf16*)(ws + 144*MB + 512*1024);
  char*   smallp = ws + 145*MB;
  int*   idx0     = (int*)smallp;
  int*   idx1     = idx0 + NTOK;
  float* g0       = (float*)(idx1 + NTOK);
  float* g1       = g0 + NTOK;
  int*   tok_slot = (int*)(g1 + NTOK);
  int*   idx_buf  = tok_slot + NTOK*2;

  // 1. LN1 -> hi/lo bf16
  ln_split<<<dim3(NTOK/4), dim3(64,4), 0, stream>>>(x, ln1g, ln1b, h1hi, h1lo);
  // 2. weight packing/transposes
  pack_qkv_split<<<dim3(8,24), 256, 0, stream>>>(Wq, Wk, Wv, Bqh, Bql);
  transp_split<<<dim3(8,8), 256, 0, stream>>>(Wo, WoTh, WoTl, DD, DD);
  // 3. QKV projection (bf16x3 MFMA)
  gemm_mfma3<0,0><<<dim3(12,64), 256, 0, stream>>>(h1hi, h1lo, Bqh, Bql, nullptr, nullptr, qkv, NTOK, 1536, DD);
  // 4a. convert K,V -> hi/lo bf16 (V transposed)
  convert_kv<<<dim3(TSEQ/64, 32), 256, 0, stream>>>(qkv, Khi, Klo, Vthi, Vtlo);
  // 4b. causal flash attention
  attn_mfma<<<dim3(32, 8), 512, 0, stream>>>(qkv, Khi, Klo, Vthi, Vtlo, attnhi, attnlo);
  // 5. Wo projection + bias + residual -> x1
  gemm_mfma3<1,1><<<dim3(4,64), 256, 0, stream>>>(attnhi, attnlo, WoTh, WoTl, bo, x, x1, NTOK, DD, DD);
  // 6. fused LN2 + router
  routerln_kernel<<<dim3(NTOK/4), 256, 0, stream>>>(x1, ln2g, ln2b, Wg, bg, Wn, bn,
      h2b, idx0, idx1, g0, g1);
  // 7. expert weights -> bf16 transposed
  transp_conv<<<dim3(32,8,NE), 256, 0, stream>>>(W1, W1T, DD, FF);
  transp_conv<<<dim3(8,32,NE), 256, 0, stream>>>(W2, W2T, FF, DD);
  // 8. capacity scan
  route_scan<<<dim3(NE), 256, 0, stream>>>(idx0, idx1, idx_buf, tok_slot);
  // 9+10. expert FFN, 2 groups of 4 experts; W1 gathers tokens directly via idx_buf
  for (int gg = 0; gg < 2; ++gg){
    gemm_mfma<1,1,1,4><<<dim3(4*16*16), 256, 0, stream>>>(
        h2b, W1T + (size_t)gg*4*DD*FF, b1 + (size_t)gg*4*FF,
        mid, idx_buf + (size_t)gg*4*CAPK, CAPK, FF, DD);
    gemm_mfma<1,0,0,2><<<dim3(4*4*16), 256, 0, stream>>>(
        mid, W2T + (size_t)gg*4*FF*DD, b2 + (size_t)gg*4*DD,
        eoutb + (size_t)gg*4*CAPK*DD, nullptr, CAPK, DD, FF);
  }
  // 11. combine + residual
  combine_kernel<<<dim3(NTOK), 128, 0, stream>>>(x1, eoutb, idx0, idx1, g0, g1, tok_slot, out);
}

// Round 8
// 384.829 us; speedup vs baseline: 1.1745x; 1.1268x over previous
//
#include <hip/hip_runtime.h>
#include <math.h>

// ---------------- problem constants ----------------
#define TSEQ 2048
#define DD   512
#define NH   8
#define HSZ  64
#define NE   8
#define NTOK 8192    // B*T
#define CAPK 2048
#define FF   2048    // 4*D

typedef __bf16 bf16x8 __attribute__((ext_vector_type(8)));
typedef float  f32x4  __attribute__((ext_vector_type(4)));
typedef unsigned int u32;
typedef u32 u32x2 __attribute__((ext_vector_type(2)));
typedef short s16x4 __attribute__((ext_vector_type(4)));

__device__ __forceinline__ void gload16(const void* g, void* l){
  __builtin_amdgcn_global_load_lds((const __attribute__((address_space(1))) u32*)g,
                                   (__attribute__((address_space(3))) u32*)l, 16, 0, 0);
}

__device__ __forceinline__ u32 pkbf(float a, float b){
  unsigned short ua = __builtin_bit_cast(unsigned short, (__bf16)a);
  unsigned short ub = __builtin_bit_cast(unsigned short, (__bf16)b);
  return (u32)ua | ((u32)ub << 16);
}

__device__ __forceinline__ s16x4 mk4(u32 a, u32 b){
  u32x2 t; t[0] = a; t[1] = b;
  return __builtin_bit_cast(s16x4, t);
}

// ============================================================
// Threefry-2x32, key = (0, 42)
// ============================================================
__device__ __forceinline__ unsigned rotl32(unsigned x, int r){ return (x<<r)|(x>>(32-r)); }

__device__ __forceinline__ void threefry2x32(unsigned c0, unsigned c1, unsigned &o0, unsigned &o1){
  const unsigned k0 = 0u, k1 = 42u;
  const unsigned k2 = k0 ^ k1 ^ 0x1BD11BDAu;
  unsigned x0 = c0 + k0, x1 = c1 + k1;
#define TFR(rot) { x0 += x1; x1 = rotl32(x1, rot); x1 ^= x0; }
  TFR(13) TFR(15) TFR(26) TFR(6)   x0 += k1; x1 += k2 + 1u;
  TFR(17) TFR(29) TFR(16) TFR(24)  x0 += k2; x1 += k0 + 2u;
  TFR(13) TFR(15) TFR(26) TFR(6)   x0 += k0; x1 += k1 + 3u;
  TFR(17) TFR(29) TFR(16) TFR(24)  x0 += k1; x1 += k2 + 4u;
  TFR(13) TFR(15) TFR(26) TFR(6)   x0 += k2; x1 += k0 + 5u;
#undef TFR
  o0 = x0; o1 = x1;
}

__device__ __forceinline__ float erfinv_f(float x){
  float w = -log1pf(-x*x);
  float p;
  if (w < 5.0f){
    w -= 2.5f;
    p = 2.81022636e-08f;
    p = fmaf(p,w, 3.43273939e-07f);
    p = fmaf(p,w,-3.5233877e-06f);
    p = fmaf(p,w,-4.39150654e-06f);
    p = fmaf(p,w, 0.00021858087f);
    p = fmaf(p,w,-0.00125372503f);
    p = fmaf(p,w,-0.00417768164f);
    p = fmaf(p,w, 0.246640727f);
    p = fmaf(p,w, 1.50140941f);
  } else {
    w = sqrtf(w) - 3.0f;
    p = -0.000200214257f;
    p = fmaf(p,w, 0.000100950558f);
    p = fmaf(p,w, 0.00134934322f);
    p = fmaf(p,w,-0.00367342844f);
    p = fmaf(p,w, 0.00573950773f);
    p = fmaf(p,w,-0.0076224613f);
    p = fmaf(p,w, 0.00943887047f);
    p = fmaf(p,w, 1.00167406f);
    p = fmaf(p,w, 2.83297682f);
  }
  return p * x;
}

// ============================================================
// LayerNorm -> hi/lo bf16 (LN1)
// ============================================================
__global__ __launch_bounds__(256) void ln_split(const float* __restrict__ x,
    const float* __restrict__ gw, const float* __restrict__ bw,
    __bf16* __restrict__ ohi, __bf16* __restrict__ olo)
{
  int row  = blockIdx.x*4 + threadIdx.y;
  int lane = threadIdx.x;
  const float* xr = x + (size_t)row*DD;
  float4 a = *(const float4*)(xr + lane*4);
  float4 c = *(const float4*)(xr + 256 + lane*4);
  float s  = a.x+a.y+a.z+a.w + c.x+c.y+c.z+c.w;
  float ss = a.x*a.x+a.y*a.y+a.z*a.z+a.w*a.w + c.x*c.x+c.y*c.y+c.z*c.z+c.w*c.w;
  #pragma unroll
  for (int off = 32; off; off >>= 1){ s += __shfl_xor(s, off); ss += __shfl_xor(ss, off); }
  float m   = s * (1.0f/DD);
  float var = ss * (1.0f/DD) - m*m;
  float r   = 1.0f / sqrtf(var + 1e-5f);
  float4 g1 = *(const float4*)(gw + lane*4);
  float4 b1 = *(const float4*)(bw + lane*4);
  float4 g2 = *(const float4*)(gw + 256 + lane*4);
  float4 b2 = *(const float4*)(bw + 256 + lane*4);
  float f1[4], f2[4];
  f1[0]=(a.x-m)*r*g1.x+b1.x; f1[1]=(a.y-m)*r*g1.y+b1.y; f1[2]=(a.z-m)*r*g1.z+b1.z; f1[3]=(a.w-m)*r*g1.w+b1.w;
  f2[0]=(c.x-m)*r*g2.x+b2.x; f2[1]=(c.y-m)*r*g2.y+b2.y; f2[2]=(c.z-m)*r*g2.z+b2.z; f2[3]=(c.w-m)*r*g2.w+b2.w;
  __bf16 h1v[4] __attribute__((aligned(8))), l1v[4] __attribute__((aligned(8)));
  __bf16 h2v[4] __attribute__((aligned(8))), l2v[4] __attribute__((aligned(8)));
  #pragma unroll
  for (int j = 0; j < 4; ++j){
    __bf16 hb = (__bf16)f1[j]; h1v[j]=hb; l1v[j]=(__bf16)(f1[j]-(float)hb);
    __bf16 hc = (__bf16)f2[j]; h2v[j]=hc; l2v[j]=(__bf16)(f2[j]-(float)hc);
  }
  size_t base = (size_t)row*DD + lane*4;
  *(uint2*)(ohi + base)       = *(const uint2*)h1v;
  *(uint2*)(olo + base)       = *(const uint2*)l1v;
  *(uint2*)(ohi + base + 256) = *(const uint2*)h2v;
  *(uint2*)(olo + base + 256) = *(const uint2*)l2v;
}

// ============================================================
// Pack Wq|Wk|Wv (H,D,HS) -> transposed hi/lo bf16 [1536][512]
// ============================================================
__global__ __launch_bounds__(256) void pack_qkv_split(const float* __restrict__ Wq,
    const float* __restrict__ Wk, const float* __restrict__ Wv,
    __bf16* __restrict__ dhi, __bf16* __restrict__ dlo)
{
  __shared__ float t[64][65];
  int z = blockIdx.y;
  int kt = blockIdx.x*64;
  int sel = z >> 3, hh = z & 7;
  const float* W = (sel==0 ? Wq : (sel==1 ? Wk : Wv)) + (size_t)hh*DD*HSZ;
  int tid = threadIdx.x;
  int r = tid>>2, c0 = (tid&3)*16;
  #pragma unroll
  for (int j = 0; j < 16; j += 4){
    float4 v = *(const float4*)&W[(size_t)(kt+r)*HSZ + c0 + j];
    t[r][c0+j]=v.x; t[r][c0+j+1]=v.y; t[r][c0+j+2]=v.z; t[r][c0+j+3]=v.w;
  }
  __syncthreads();
  __bf16 hb[16] __attribute__((aligned(32)));
  __bf16 lb[16] __attribute__((aligned(32)));
  #pragma unroll
  for (int j = 0; j < 16; ++j){
    float f = t[c0+j][r];
    __bf16 h = (__bf16)f; hb[j]=h; lb[j]=(__bf16)(f-(float)h);
  }
  size_t off = (size_t)(z*64 + r)*512 + kt + c0;
  *(uint4*)(dhi+off) = ((const uint4*)hb)[0]; *(uint4*)(dhi+off+8) = ((const uint4*)hb)[1];
  *(uint4*)(dlo+off) = ((const uint4*)lb)[0]; *(uint4*)(dlo+off+8) = ((const uint4*)lb)[1];
}

// ============================================================
// Generic transpose + hi/lo split (Wo)
// ============================================================
__global__ __launch_bounds__(256) void transp_split(const float* __restrict__ src,
    __bf16* __restrict__ dhi, __bf16* __restrict__ dlo, int Ms, int Ns)
{
  __shared__ float t[64][65];
  int nt = blockIdx.x*64, mt = blockIdx.y*64;
  int tid = threadIdx.x;
  int r = tid>>2, c0 = (tid&3)*16;
  #pragma unroll
  for (int j = 0; j < 16; j += 4){
    float4 v = *(const float4*)&src[(size_t)(mt+r)*Ns + nt + c0 + j];
    t[r][c0+j]=v.x; t[r][c0+j+1]=v.y; t[r][c0+j+2]=v.z; t[r][c0+j+3]=v.w;
  }
  __syncthreads();
  __bf16 hb[16] __attribute__((aligned(32)));
  __bf16 lb[16] __attribute__((aligned(32)));
  #pragma unroll
  for (int j = 0; j < 16; ++j){
    float f = t[c0+j][r];
    __bf16 h = (__bf16)f; hb[j]=h; lb[j]=(__bf16)(f-(float)h);
  }
  size_t off = (size_t)(nt + r)*Ms + mt + c0;
  *(uint4*)(dhi+off) = ((const uint4*)hb)[0]; *(uint4*)(dhi+off+8) = ((const uint4*)hb)[1];
  *(uint4*)(dlo+off) = ((const uint4*)lb)[0]; *(uint4*)(dlo+off+8) = ((const uint4*)lb)[1];
}

// ============================================================
// bf16x3 split-precision MFMA GEMM, 2-phase double-buffered. (R4 proven)
// ============================================================
template<int BIAS, int RES>
__global__ __launch_bounds__(256) void gemm_mfma3(
    const __bf16* __restrict__ Ahi, const __bf16* __restrict__ Alo,
    const __bf16* __restrict__ Bhi, const __bf16* __restrict__ Blo,
    const float* __restrict__ bias, const float* __restrict__ res,
    float* __restrict__ C, int M, int N, int K)
{
  __shared__ __bf16 AsH[2][4096];
  __shared__ __bf16 AsL[2][4096];
  __shared__ __bf16 BsH[2][4096];
  __shared__ __bf16 BsL[2][4096];
  int m0 = blockIdx.y*128, n0 = blockIdx.x*128;
  int tid = threadIdx.x;
  int w = tid>>6, l = tid&63;
  int wm = w>>1, wn = w&1;
  int srow = w*32 + (l>>2);
  int skb  = (l&3)<<4;
  const char* agh = (const char*)(Ahi + (size_t)(m0+srow)*K) + skb;
  const char* agl = (const char*)(Alo + (size_t)(m0+srow)*K) + skb;
  const char* bgh = (const char*)(Bhi + (size_t)(n0+srow)*K) + skb;
  const char* bgl = (const char*)(Blo + (size_t)(n0+srow)*K) + skb;
  size_t r16 = (size_t)16*K*sizeof(__bf16);

  f32x4 acc[4][4] = {};
  int rl = l & 15, kh = l >> 4;
  const __bf16* abh = &AsH[0][(wm*64 + rl)*32 + kh*8];
  const __bf16* abl = &AsL[0][(wm*64 + rl)*32 + kh*8];
  const __bf16* bbh = &BsH[0][(wn*64 + rl)*32 + kh*8];
  const __bf16* bbl = &BsL[0][(wn*64 + rl)*32 + kh*8];

  auto STAGE = [&](int bb, int kt){
    size_t o = (size_t)kt*64;
    gload16(agh+o,     &AsH[bb][w*1024]);
    gload16(agh+o+r16, &AsH[bb][w*1024+512]);
    gload16(agl+o,     &AsL[bb][w*1024]);
    gload16(agl+o+r16, &AsL[bb][w*1024+512]);
    gload16(bgh+o,     &BsH[bb][w*1024]);
    gload16(bgh+o+r16, &BsH[bb][w*1024+512]);
    gload16(bgl+o,     &BsL[bb][w*1024]);
    gload16(bgl+o+r16, &BsL[bb][w*1024+512]);
  };

  int nkt = K >> 5;
  STAGE(0, 0);
  __syncthreads();
  for (int kt = 0; kt < nkt; ++kt){
    int bb = kt & 1;
    if (kt + 1 < nkt) STAGE(bb^1, kt+1);
    bf16x8 afh[4], afl[4], bfh[4], bfl[4];
    #pragma unroll
    for (int i = 0; i < 4; ++i){
      afh[i] = *(const bf16x8*)(abh + bb*4096 + i*512);
      afl[i] = *(const bf16x8*)(abl + bb*4096 + i*512);
      bfh[i] = *(const bf16x8*)(bbh + bb*4096 + i*512);
      bfl[i] = *(const bf16x8*)(bbl + bb*4096 + i*512);
    }
    #pragma unroll
    for (int fm = 0; fm < 4; ++fm)
      #pragma unroll
      for (int fn = 0; fn < 4; ++fn){
        acc[fm][fn] = __builtin_amdgcn_mfma_f32_16x16x32_bf16(afh[fm], bfl[fn], acc[fm][fn], 0, 0, 0);
        acc[fm][fn] = __builtin_amdgcn_mfma_f32_16x16x32_bf16(afl[fm], bfh[fn], acc[fm][fn], 0, 0, 0);
        acc[fm][fn] = __builtin_amdgcn_mfma_f32_16x16x32_bf16(afh[fm], bfh[fn], acc[fm][fn], 0, 0, 0);
      }
    __syncthreads();
  }

  int ccol = l & 15, cr = (l >> 4) * 4;
  #pragma unroll
  for (int fn = 0; fn < 4; ++fn){
    int n = n0 + wn*64 + fn*16 + ccol;
    float bv = BIAS ? bias[n] : 0.0f;
    #pragma unroll
    for (int fm = 0; fm < 4; ++fm){
      int mb = m0 + wm*64 + fm*16 + cr;
      #pragma unroll
      for (int r = 0; r < 4; ++r){
        float v = acc[fm][fn][r] + bv;
        if (RES) v += res[(size_t)(mb+r)*N + n];
        C[(size_t)(mb+r)*N + n] = v;
      }
    }
  }
}

// ============================================================
// bf16 MFMA GEMM (experts), 2-phase double-buffered, 1-D grid with
// expert = flat & (2^EBITS-1) (XCD locality), optional gather-indirect A.
// grid = 2^EBITS experts * (M/128 * 2^LOGN) blocks.
// ============================================================
template<int STORE_BF16, int RELU, int GATHER, int LOGN, int EBITS>
__global__ __launch_bounds__(256) void gemm_mfma(
    const __bf16* __restrict__ A, const __bf16* __restrict__ Bt,
    const float* __restrict__ bias, void* __restrict__ Cv,
    const int* __restrict__ idxb, int M, int N, int K)
{
  __shared__ __bf16 Asl[2][4096];
  __shared__ __bf16 Bsl[2][4096];
  int flat = blockIdx.x;
  int e = flat & ((1<<EBITS)-1);
  int tile = flat >> EBITS;
  int n0 = (tile & ((1<<LOGN)-1)) * 128;
  int m0 = (tile >> LOGN) * 128;
  const __bf16* Be = Bt + (size_t)e*N*K;
  const float*  be = bias + (size_t)e*N;
  int tid = threadIdx.x;
  int w = tid>>6, l = tid&63;
  int wm = w>>1, wn = w&1;
  int srow = w*32 + (l>>2);
  int skb  = (l&3)<<4;
  const char* ag;
  if (GATHER){
    int tok = idxb[e*CAPK + m0 + srow];
    ag = (const char*)(A + (size_t)tok*K) + skb;
  } else {
    ag = (const char*)(A + (size_t)e*M*K + (size_t)(m0 + srow)*K) + skb;
  }
  const char* bg = (const char*)(Be + (size_t)(n0 + srow)*K) + skb;
  size_t r16;
  if (GATHER){
    int tok2 = idxb[e*CAPK + m0 + srow + 16];
    r16 = (size_t)((const char*)(A + (size_t)tok2*K) + skb - ag);
  } else {
    r16 = (size_t)16*K*sizeof(__bf16);
  }

  f32x4 acc[4][4] = {};
  int rl = l & 15, kh = l >> 4;
  const __bf16* abase = &Asl[0][(wm*64 + rl)*32 + kh*8];
  const __bf16* bbase = &Bsl[0][(wn*64 + rl)*32 + kh*8];

  size_t br16 = (size_t)16*K*sizeof(__bf16);
  auto STAGE = [&](int bb, int kt){
    size_t o = (size_t)kt*64;
    gload16(ag+o,      &Asl[bb][w*1024]);
    gload16(ag+o+r16,  &Asl[bb][w*1024+512]);
    gload16(bg+o,      &Bsl[bb][w*1024]);
    gload16(bg+o+br16, &Bsl[bb][w*1024+512]);
  };

  int nkt = K >> 5;
  STAGE(0, 0);
  __syncthreads();
  for (int kt = 0; kt < nkt; ++kt){
    int bb = kt & 1;
    if (kt + 1 < nkt) STAGE(bb^1, kt+1);
    bf16x8 af[4], bf[4];
    #pragma unroll
    for (int i = 0; i < 4; ++i){
      af[i] = *(const bf16x8*)(abase + bb*4096 + i*512);
      bf[i] = *(const bf16x8*)(bbase + bb*4096 + i*512);
    }
    #pragma unroll
    for (int fm = 0; fm < 4; ++fm)
      #pragma unroll
      for (int fn = 0; fn < 4; ++fn)
        acc[fm][fn] = __builtin_amdgcn_mfma_f32_16x16x32_bf16(af[fm], bf[fn], acc[fm][fn], 0, 0, 0);
    __syncthreads();
  }

  int ccol = l & 15, cr = (l >> 4) * 4;
  char* Ce = (char*)Cv + (size_t)e*M*N*(STORE_BF16 ? 2 : 4);
  #pragma unroll
  for (int fn = 0; fn < 4; ++fn){
    int n = n0 + wn*64 + fn*16 + ccol;
    float bv = be[n];
    #pragma unroll
    for (int fm = 0; fm < 4; ++fm){
      int mb = m0 + wm*64 + fm*16 + cr;
      #pragma unroll
      for (int r = 0; r < 4; ++r){
        float v = acc[fm][fn][r] + bv;
        if (RELU) v = fmaxf(v, 0.f);
        if (STORE_BF16) ((__bf16*)Ce)[(size_t)(mb+r)*N + n] = (__bf16)v;
        else            ((float*)Ce)[(size_t)(mb+r)*N + n] = v;
      }
    }
  }
}

// ============================================================
// Transpose + convert expert weights (f32 -> plain bf16 [N][K])
// ============================================================
__global__ __launch_bounds__(256) void transp_conv(const float* __restrict__ src,
    __bf16* __restrict__ dst, int Ms, int Ns)
{
  __shared__ __bf16 t[64][72];
  int e = blockIdx.z;
  const float* s = src + (size_t)e*Ms*Ns;
  __bf16* d = dst + (size_t)e*Ms*Ns;
  int mt = blockIdx.y*64, nt = blockIdx.x*64;
  int tid = threadIdx.x;
  int r = tid>>2, c0 = (tid&3)*16;
  #pragma unroll
  for (int j = 0; j < 16; j += 4){
    float4 v = *(const float4*)&s[(size_t)(mt+r)*Ns + nt + c0 + j];
    t[r][c0+j]   = (__bf16)v.x; t[r][c0+j+1] = (__bf16)v.y;
    t[r][c0+j+2] = (__bf16)v.z; t[r][c0+j+3] = (__bf16)v.w;
  }
  __syncthreads();
  __bf16 tmp[16] __attribute__((aligned(32)));
  #pragma unroll
  for (int j = 0; j < 16; ++j) tmp[j] = t[c0+j][r];
  uint4* dp = (uint4*)&d[(size_t)(nt+r)*Ms + mt + c0];
  dp[0] = ((const uint4*)tmp)[0];
  dp[1] = ((const uint4*)tmp)[1];
}

// ============================================================
// Convert K,V (f32 in qkv) to hi/lo bf16; V transposed. (R4 proven)
// ============================================================
__global__ __launch_bounds__(256) void convert_kv(const float* __restrict__ qkv,
    __bf16* __restrict__ khi, __bf16* __restrict__ klo,
    __bf16* __restrict__ vthi, __bf16* __restrict__ vtlo)
{
  int t0 = blockIdx.x*64;
  int bh = blockIdx.y;
  int b = bh >> 3, h = bh & 7;
  int tid = threadIdx.x;
  {
    int r = tid >> 2, e0 = (tid & 3) * 16;
    const float* src = qkv + ((size_t)(b*TSEQ + t0 + r))*1536 + 512 + h*64 + e0;
    __bf16 hi[16] __attribute__((aligned(16)));
    __bf16 lo[16] __attribute__((aligned(16)));
    #pragma unroll
    for (int j = 0; j < 16; j += 4){
      float4 v = *(const float4*)(src + j);
      float f[4] = {v.x, v.y, v.z, v.w};
      #pragma unroll
      for (int q = 0; q < 4; ++q){
        __bf16 hb = (__bf16)f[q];
        hi[j+q] = hb; lo[j+q] = (__bf16)(f[q] - (float)hb);
      }
    }
    size_t off = ((size_t)(bh*TSEQ + t0 + r))*64 + e0;
    *(uint4*)(khi + off)     = ((const uint4*)hi)[0];
    *(uint4*)(khi + off + 8) = ((const uint4*)hi)[1];
    *(uint4*)(klo + off)     = ((const uint4*)lo)[0];
    *(uint4*)(klo + off + 8) = ((const uint4*)lo)[1];
  }
  {
    int key0 = (tid & 15) * 4, e0 = (tid >> 4) * 4;
    float4 v[4];
    #pragma unroll
    for (int j = 0; j < 4; ++j)
      v[j] = *(const float4*)(qkv + ((size_t)(b*TSEQ + t0 + key0 + j))*1536 + 1024 + h*64 + e0);
    float col[4][4];
    col[0][0]=v[0].x; col[0][1]=v[1].x; col[0][2]=v[2].x; col[0][3]=v[3].x;
    col[1][0]=v[0].y; col[1][1]=v[1].y; col[1][2]=v[2].y; col[1][3]=v[3].y;
    col[2][0]=v[0].z; col[2][1]=v[1].z; col[2][2]=v[2].z; col[2][3]=v[3].z;
    col[3][0]=v[0].w; col[3][1]=v[1].w; col[3][2]=v[2].w; col[3][3]=v[3].w;
    #pragma unroll
    for (int kk = 0; kk < 4; ++kk){
      __bf16 hi[4] __attribute__((aligned(8)));
      __bf16 lo[4] __attribute__((aligned(8)));
      #pragma unroll
      for (int j = 0; j < 4; ++j){
        __bf16 hb = (__bf16)col[kk][j];
        hi[j] = hb; lo[j] = (__bf16)(col[kk][j] - (float)hb);
      }
      size_t off = ((size_t)(bh*64 + e0 + kk))*TSEQ + t0 + key0;
      *(uint2*)(vthi + off) = *(const uint2*)hi;
      *(uint2*)(vtlo + off) = *(const uint2*)lo;
    }
  }
}

// ============================================================
// bf16x3 MFMA flash attention (causal), transposed compute.
// PV uses mfma_f32_16x16x16_bf16 (K=16): its B-frag k-layout (4g+j)
// matches QK^T's D-layout exactly -> packed P pairs feed PV directly,
// no cross-lane shuffles.
// ============================================================
__global__ __launch_bounds__(512) void attn_mfma(const float* __restrict__ qkv,
    const __bf16* __restrict__ khi_g, const __bf16* __restrict__ klo_g,
    const __bf16* __restrict__ vthi_g, const __bf16* __restrict__ vtlo_g,
    __bf16* __restrict__ ahi, __bf16* __restrict__ alo)
{
  __shared__ __align__(16) char ldsbuf[65536];   // [2 buf][4 arr][8KB]
  int bh = blockIdx.x;
  int qtA = blockIdx.y, qtB = 15 - qtA;
  int b = bh >> 3, h = bh & 7;
  int tid = threadIdx.x;
  int w = tid >> 6, l = tid & 63;
  int g = l >> 4, r = l & 15;
  const float qsc = 0.04419417382415922f * 1.4426950408889634f;  // D^-0.5 * log2(e)

  int qb[2]; qb[0] = qtA*128 + w*16; qb[1] = qtB*128 + (7-w)*16;
  int kdiag[2]; kdiag[0] = qb[0] >> 6; kdiag[1] = qb[1] >> 6;

  bf16x8 qhi[2][2], qlo[2][2];
  #pragma unroll
  for (int qf = 0; qf < 2; ++qf)
    #pragma unroll
    for (int ks = 0; ks < 2; ++ks){
      const float* src = qkv + ((size_t)(b*TSEQ + qb[qf] + r))*1536 + h*64 + ks*32 + g*8;
      float4 v0 = *(const float4*)src;
      float4 v1 = *(const float4*)(src + 4);
      float f[8] = {v0.x,v0.y,v0.z,v0.w,v1.x,v1.y,v1.z,v1.w};
      bf16x8 hi, lo;
      #pragma unroll
      for (int i = 0; i < 8; ++i){
        float fs = f[i] * qsc;
        __bf16 hb = (__bf16)fs;
        hi[i] = hb; lo[i] = (__bf16)(fs - (float)hb);
      }
      qhi[qf][ks] = hi; qlo[qf][ks] = lo;
    }

  f32x4 ot[4][2] = {};
  float m_r[2] = {-INFINITY, -INFINITY};
  float l_r[2] = {0.f, 0.f};

  int nkt = 2*qtB + 2;
  size_t kbase = (size_t)bh*TSEQ*64;
  size_t vbase = (size_t)bh*64*TSEQ;

  auto STAGE = [&](int buf, int kt){
    int row = tid >> 3, cc = tid & 7;
    int sw = (cc ^ (row & 7)) * 8;
    char* d = ldsbuf + buf*32768 + (w << 10);
    gload16(khi_g  + kbase + (size_t)(kt*64 + row)*64 + sw, d);
    gload16(klo_g  + kbase + (size_t)(kt*64 + row)*64 + sw, d + 8192);
    gload16(vthi_g + vbase + (size_t)row*TSEQ + kt*64 + sw,  d + 16384);
    gload16(vtlo_g + vbase + (size_t)row*TSEQ + kt*64 + sw,  d + 24576);
  };

  STAGE(0, 0);
  __syncthreads();

  for (int kt = 0; kt < nkt; ++kt){
    int buf = kt & 1;
    if (kt + 1 < nkt) STAGE(buf ^ 1, kt + 1);

    bool act[2];
    act[0] = (kt <= kdiag[0]);
    act[1] = (kt <= kdiag[1]);

    const char* K0 = ldsbuf + buf*32768;
    const char* K1 = K0 + 8192;
    const char* V0 = K0 + 16384;
    const char* V1 = K0 + 24576;

    // ---- S^T = K · Q^T (bf16x3) ----
    f32x4 s[4][2] = {};
    #pragma unroll
    for (int kf = 0; kf < 4; ++kf){
      int rowk = kf*16 + r;
      int rsw = (rowk & 7) << 4;
      #pragma unroll
      for (int ks = 0; ks < 2; ++ks){
        int off = rowk*128 + ((((ks*4 + g) << 4)) ^ rsw);
        bf16x8 khf = *(const bf16x8*)(K0 + off);
        bf16x8 klf = *(const bf16x8*)(K1 + off);
        #pragma unroll
        for (int qf = 0; qf < 2; ++qf){
          if (act[qf]){
            s[kf][qf] = __builtin_amdgcn_mfma_f32_16x16x32_bf16(khf, qlo[qf][ks], s[kf][qf], 0,0,0);
            s[kf][qf] = __builtin_amdgcn_mfma_f32_16x16x32_bf16(klf, qhi[qf][ks], s[kf][qf], 0,0,0);
            s[kf][qf] = __builtin_amdgcn_mfma_f32_16x16x32_bf16(khf, qhi[qf][ks], s[kf][qf], 0,0,0);
          }
        }
      }
    }

    // ---- mask (diag tile only) + online softmax (exp2, defer-max) ----
    u32 phi[4][2][2], plo[4][2][2];
    #pragma unroll
    for (int qf = 0; qf < 2; ++qf){
      if (act[qf]){
        int q = qb[qf] + r;
        float p[4][4];
        float mx = -INFINITY;
        if (kt == kdiag[qf]){
          #pragma unroll
          for (int kf = 0; kf < 4; ++kf)
            #pragma unroll
            for (int e = 0; e < 4; ++e){
              int key = kt*64 + kf*16 + g*4 + e;
              float sv = (key <= q) ? s[kf][qf][e] : -INFINITY;
              p[kf][e] = sv;
              mx = fmaxf(mx, sv);
            }
        } else {
          #pragma unroll
          for (int kf = 0; kf < 4; ++kf)
            #pragma unroll
            for (int e = 0; e < 4; ++e){
              float sv = s[kf][qf][e];
              p[kf][e] = sv;
              mx = fmaxf(mx, sv);
            }
        }
        mx = fmaxf(mx, __shfl_xor(mx, 16));
        mx = fmaxf(mx, __shfl_xor(mx, 32));
        if (__any(mx > m_r[qf])){
          float mn = fmaxf(m_r[qf], mx);
          float fj = exp2f(m_r[qf] - mn);
          m_r[qf] = mn;
          l_r[qf] *= fj;
          #pragma unroll
          for (int ef = 0; ef < 4; ++ef)
            #pragma unroll
            for (int e = 0; e < 4; ++e)
              ot[ef][qf][e] *= fj;
        }
        float ts = 0.f;
        #pragma unroll
        for (int kf = 0; kf < 4; ++kf)
          #pragma unroll
          for (int e = 0; e < 4; ++e){
            float pv = exp2f(p[kf][e] - m_r[qf]);
            p[kf][e] = pv; ts += pv;
          }
        ts += __shfl_xor(ts, 16); ts += __shfl_xor(ts, 32);
        l_r[qf] += ts;
        #pragma unroll
        for (int kf = 0; kf < 4; ++kf){
          __bf16 h0=(__bf16)p[kf][0], h1=(__bf16)p[kf][1], h2=(__bf16)p[kf][2], h3=(__bf16)p[kf][3];
          phi[kf][qf][0] = pkbf(p[kf][0], p[kf][1]);
          phi[kf][qf][1] = pkbf(p[kf][2], p[kf][3]);
          plo[kf][qf][0] = pkbf(p[kf][0]-(float)h0, p[kf][1]-(float)h1);
          plo[kf][qf][1] = pkbf(p[kf][2]-(float)h2, p[kf][3]-(float)h3);
        }
      }
    }

    // ---- O^T += V^T · P^T via K=16 MFMA; P frags direct from registers ----
    #pragma unroll
    for (int kf = 0; kf < 4; ++kf){
      #pragma unroll
      for (int ef = 0; ef < 4; ++ef){
        int rowv = ef*16 + r;
        int off = rowv*128 + ((((2*kf + (g>>1)) ^ (rowv & 7)) << 4)) + (g&1)*8;
        s16x4 vh = *(const s16x4*)(V0 + off);
        s16x4 vl = *(const s16x4*)(V1 + off);
        #pragma unroll
        for (int qf = 0; qf < 2; ++qf){
          if (act[qf]){
            s16x4 ph = mk4(phi[kf][qf][0], phi[kf][qf][1]);
            s16x4 pl = mk4(plo[kf][qf][0], plo[kf][qf][1]);
            ot[ef][qf] = __builtin_amdgcn_mfma_f32_16x16x16bf16_1k(vh, pl, ot[ef][qf], 0,0,0);
            ot[ef][qf] = __builtin_amdgcn_mfma_f32_16x16x16bf16_1k(vl, ph, ot[ef][qf], 0,0,0);
            ot[ef][qf] = __builtin_amdgcn_mfma_f32_16x16x16bf16_1k(vh, ph, ot[ef][qf], 0,0,0);
          }
        }
      }
    }
    __syncthreads();
  }

  float* Osh = (float*)ldsbuf;   // [128][68]
  #pragma unroll
  for (int qf = 0; qf < 2; ++qf){
    float inv = 1.0f / l_r[qf];
    int qloc = (qf ? (7-w) : w)*16 + r;
    #pragma unroll
    for (int ef = 0; ef < 4; ++ef)
      #pragma unroll
      for (int e = 0; e < 4; ++e)
        Osh[qloc*68 + ef*16 + g*4 + e] = ot[ef][qf][e] * inv;
    __syncthreads();
    {
      int qt = qf ? qtB : qtA;
      int q = tid >> 2, e0 = (tid & 3)*16;
      const float* srow = Osh + q*68 + e0;
      size_t base = ((size_t)(b*TSEQ + qt*128 + q))*DD + h*64 + e0;
      #pragma unroll
      for (int j = 0; j < 4; ++j){
        float4 v = *(const float4*)(srow + j*4);
        float f[4] = {v.x, v.y, v.z, v.w};
        __bf16 hb[4] __attribute__((aligned(8)));
        __bf16 lb[4] __attribute__((aligned(8)));
        #pragma unroll
        for (int q2 = 0; q2 < 4; ++q2){
          __bf16 h2b = (__bf16)f[q2];
          hb[q2] = h2b; lb[q2] = (__bf16)(f[q2] - (float)h2b);
        }
        *(uint2*)(ahi + base + j*4) = *(const uint2*)hb;
        *(uint2*)(alo + base + j*4) = *(const uint2*)lb;
      }
    }
    __syncthreads();
  }
}

// ============================================================
// Fused LN2 + Router: reads x1, writes h2 (bf16) + routing
// ============================================================
__global__ __launch_bounds__(256) void routerln_kernel(const float* __restrict__ x1,
    const float* __restrict__ gw, const float* __restrict__ bw,
    const float* __restrict__ Wg, const float* __restrict__ bg,
    const float* __restrict__ Wn, const float* __restrict__ bn,
    __bf16* __restrict__ h2b,
    int* __restrict__ idx0, int* __restrict__ idx1,
    float* __restrict__ g0, float* __restrict__ g1)
{
  int wid = threadIdx.x >> 6, lane = threadIdx.x & 63;
  int tok = blockIdx.x*4 + wid;
  const float* xr = x1 + (size_t)tok*DD;
  float4 a = *(const float4*)(xr + lane*4);
  float4 c = *(const float4*)(xr + 256 + lane*4);
  float s  = a.x+a.y+a.z+a.w + c.x+c.y+c.z+c.w;
  float ss = a.x*a.x+a.y*a.y+a.z*a.z+a.w*a.w + c.x*c.x+c.y*c.y+c.z*c.z+c.w*c.w;
  #pragma unroll
  for (int off = 32; off; off >>= 1){ s += __shfl_xor(s, off); ss += __shfl_xor(ss, off); }
  float m   = s * (1.0f/DD);
  float var = ss * (1.0f/DD) - m*m;
  float rr  = 1.0f / sqrtf(var + 1e-5f);
  float4 g1v = *(const float4*)(gw + lane*4);
  float4 b1v = *(const float4*)(bw + lane*4);
  float4 g2v = *(const float4*)(gw + 256 + lane*4);
  float4 b2v = *(const float4*)(bw + 256 + lane*4);
  float f1[4], f2[4];
  f1[0]=(a.x-m)*rr*g1v.x+b1v.x; f1[1]=(a.y-m)*rr*g1v.y+b1v.y; f1[2]=(a.z-m)*rr*g1v.z+b1v.z; f1[3]=(a.w-m)*rr*g1v.w+b1v.w;
  f2[0]=(c.x-m)*rr*g2v.x+b2v.x; f2[1]=(c.y-m)*rr*g2v.y+b2v.y; f2[2]=(c.z-m)*rr*g2v.z+b2v.z; f2[3]=(c.w-m)*rr*g2v.w+b2v.w;
  {
    __bf16 h1v[4] __attribute__((aligned(8)));
    __bf16 h2v[4] __attribute__((aligned(8)));
    #pragma unroll
    for (int j = 0; j < 4; ++j){ h1v[j] = (__bf16)f1[j]; h2v[j] = (__bf16)f2[j]; }
    size_t base = (size_t)tok*DD + lane*4;
    *(uint2*)(h2b + base)       = *(const uint2*)h1v;
    *(uint2*)(h2b + base + 256) = *(const uint2*)h2v;
  }
  float ag[8] = {0,0,0,0,0,0,0,0}, an[8] = {0,0,0,0,0,0,0,0};
  int d1 = lane*4, d2 = 256 + lane*4;
  #pragma unroll
  for (int j = 0; j < 4; ++j){
    const float* wg1 = Wg + (size_t)(d1+j)*8;
    const float* wn1 = Wn + (size_t)(d1+j)*8;
    const float* wg2 = Wg + (size_t)(d2+j)*8;
    const float* wn2 = Wn + (size_t)(d2+j)*8;
    #pragma unroll
    for (int e = 0; e < 8; ++e){
      ag[e] = fmaf(f1[j], wg1[e], ag[e]); an[e] = fmaf(f1[j], wn1[e], an[e]);
      ag[e] = fmaf(f2[j], wg2[e], ag[e]); an[e] = fmaf(f2[j], wn2[e], an[e]);
    }
  }
  #pragma unroll
  for (int off = 32; off; off >>= 1){
    #pragma unroll
    for (int e = 0; e < 8; ++e){ ag[e] += __shfl_xor(ag[e], off); an[e] += __shfl_xor(an[e], off); }
  }
  __shared__ float ns[4][8];
  if (lane < 8){
    int e = lane;
    float lg = ag[e] + bg[e];
    float nl = an[e] + bn[e];
    float sp = fmaxf(nl, 0.f) + log1pf(expf(-fabsf(nl)));
    unsigned i = (unsigned)(tok*8 + e);
    unsigned r0b, r1b;
    threefry2x32(0u, i, r0b, r1b);
    unsigned bits = r0b ^ r1b;
    float f = __uint_as_float((bits >> 9) | 0x3f800000u) - 1.0f;
    float u = fmaf(f, 2.0f, -0.99999994f);
    u = fmaxf(u, -0.99999994f);
    float z = 1.41421356f * erfinv_f(u);
    ns[wid][e] = lg + z*sp;
  }
  __syncthreads();
  if (lane == 0){
    float v0 = -INFINITY; int i0 = 0;
    #pragma unroll
    for (int e = 0; e < 8; ++e){ float v = ns[wid][e]; if (v > v0){ v0 = v; i0 = e; } }
    float v1 = -INFINITY; int i1 = 0;
    #pragma unroll
    for (int e = 0; e < 8; ++e){ if (e != i0){ float v = ns[wid][e]; if (v > v1){ v1 = v; i1 = e; } } }
    float dexp = expf(v1 - v0);
    float ssum = 1.0f + dexp;
    idx0[tok] = i0; idx1[tok] = i1;
    g0[tok] = 1.0f/ssum; g1[tok] = dexp/ssum;
  }
}

// ============================================================
// Capacity routing
// ============================================================
__global__ __launch_bounds__(256) void route_scan(const int* __restrict__ idx0,
    const int* __restrict__ idx1, int* __restrict__ idx_buf, int* __restrict__ tok_slot)
{
  int e = blockIdx.x, tid = threadIdx.x;
  for (int i = tid; i < CAPK; i += 256) idx_buf[e*CAPK + i] = 0;
  __syncthreads();
  int base = tid * 32;
  int cnt = 0;
  for (int j = 0; j < 32; ++j){ int t = base + j; cnt += (idx0[t]==e || idx1[t]==e) ? 1 : 0; }
  __shared__ int ps[256];
  ps[tid] = cnt; __syncthreads();
  for (int off = 1; off < 256; off <<= 1){
    int add = (tid >= off) ? ps[tid - off] : 0;
    __syncthreads();
    ps[tid] += add;
    __syncthreads();
  }
  int slot = ps[tid] - cnt;
  for (int j = 0; j < 32; ++j){
    int t = base + j;
    int k = (idx0[t]==e) ? 0 : ((idx1[t]==e) ? 1 : -1);
    if (k >= 0){
      if (slot < CAPK){ idx_buf[e*CAPK + slot] = t; tok_slot[t*2 + k] = slot; }
      else            { tok_slot[t*2 + k] = -1; }
      slot++;
    }
  }
}

// ============================================================
// Combine (eout bf16)
// ============================================================
__global__ __launch_bounds__(128) void combine_kernel(const float* __restrict__ x1,
    const __bf16* __restrict__ eout, const int* __restrict__ idx0, const int* __restrict__ idx1,
    const float* __restrict__ g0, const float* __restrict__ g1,
    const int* __restrict__ tok_slot, float* __restrict__ outp)
{
  int n = blockIdx.x, t = threadIdx.x;
  float4 acc = *(const float4*)(x1 + (size_t)n*DD + t*4);
  #pragma unroll
  for (int k = 0; k < 2; ++k){
    int s = tok_slot[n*2 + k];
    if (s >= 0){
      int e  = (k==0) ? idx0[n] : idx1[n];
      float g = (k==0) ? g0[n] : g1[n];
      __bf16 vb[4] __attribute__((aligned(8)));
      *(uint2*)vb = *(const uint2*)(eout + ((size_t)(e*CAPK + s))*DD + t*4);
      acc.x = fmaf(g, (float)vb[0], acc.x); acc.y = fmaf(g, (float)vb[1], acc.y);
      acc.z = fmaf(g, (float)vb[2], acc.z); acc.w = fmaf(g, (float)vb[3], acc.w);
    }
  }
  *(float4*)(outp + (size_t)n*DD + t*4) = acc;
}

// ============================================================
extern "C" void kernel_launch(void* const* d_in, const int* in_sizes, int n_in,
                              void* d_out, int out_size, void* d_ws, size_t ws_size,
                              hipStream_t stream)
{
  const float* x    = (const float*)d_in[0];
  const float* ln1g = (const float*)d_in[1];
  const float* ln1b = (const float*)d_in[2];
  const float* Wq   = (const float*)d_in[3];
  const float* Wk   = (const float*)d_in[4];
  const float* Wv   = (const float*)d_in[5];
  const float* Wo   = (const float*)d_in[6];
  const float* bo   = (const float*)d_in[7];
  const float* ln2g = (const float*)d_in[8];
  const float* ln2b = (const float*)d_in[9];
  const float* Wg   = (const float*)d_in[10];
  const float* bg   = (const float*)d_in[11];
  const float* Wn   = (const float*)d_in[12];
  const float* bn   = (const float*)d_in[13];
  const float* W1   = (const float*)d_in[14];
  const float* b1   = (const float*)d_in[15];
  const float* W2   = (const float*)d_in[16];
  const float* b2   = (const float*)d_in[17];
  float* out = (float*)d_out;
  char* ws = (char*)d_ws;
  const size_t MB = 1u << 20;

  // workspace layout (time-aliased; peak ~145.5 MiB)
  __bf16* h1hi   = (__bf16*)(ws);             // 0..8   : LN1 hi (s1-3)
  __bf16* h1lo   = (__bf16*)(ws + 8*MB);      // 8..16  : LN1 lo
  __bf16* attnhi = (__bf16*)(ws);             // 0..8   : attn out hi (s4b-5)
  __bf16* attnlo = (__bf16*)(ws + 8*MB);      // 8..16
  __bf16* h2b    = (__bf16*)(ws);             // 0..8   : LN2 out bf16 (s6-10)
  float*  qkv    = (float*)(ws + 16*MB);      // 16..64 : qkv f32 (s3-4b)
  __bf16* W1T    = (__bf16*)(ws + 16*MB);     // 16..32 : (s7-10)
  __bf16* W2T    = (__bf16*)(ws + 32*MB);     // 32..48 : (s7-10)
  __bf16* eoutb  = (__bf16*)(ws + 48*MB);     // 48..64 : expert out bf16 (s10-11)
  float*  x1     = (float*)(ws + 64*MB);      // 64..80 : (s5-11)
  __bf16* Khi    = (__bf16*)(ws + 80*MB);     // 80..88 : (s4a-4b)
  __bf16* Klo    = (__bf16*)(ws + 88*MB);     // 88..96
  __bf16* Vthi   = (__bf16*)(ws + 96*MB);     // 96..104
  __bf16* Vtlo   = (__bf16*)(ws + 104*MB);    // 104..112
  __bf16* Bqh    = (__bf16*)(ws + 80*MB);     // 80..81.5 : qkv W hi (s2-3; dead before s4a)
  __bf16* Bql    = (__bf16*)(ws + 82*MB);     // 82..83.5
  __bf16* mid    = (__bf16*)(ws + 80*MB);     // 80..144 : all-8-expert mid (s10; over K/V, dead)
  __bf16* WoTh   = (__bf16*)(ws + 144*MB);    // 144..144.5 (s2-5)
  __bf16* WoTl   = (__bf16*)(ws + 144*MB + 512*1024);
  char*   smallp = ws + 145*MB;
  int*   idx0     = (int*)smallp;
  int*   idx1     = idx0 + NTOK;
  float* g0       = (float*)(idx1 + NTOK);
  float* g1       = g0 + NTOK;
  int*   tok_slot = (int*)(g1 + NTOK);
  int*   idx_buf  = tok_slot + NTOK*2;

  // 1. LN1 -> hi/lo bf16
  ln_split<<<dim3(NTOK/4), dim3(64,4), 0, stream>>>(x, ln1g, ln1b, h1hi, h1lo);
  // 2. weight packing/transposes
  pack_qkv_split<<<dim3(8,24), 256, 0, stream>>>(Wq, Wk, Wv, Bqh, Bql);
  transp_split<<<dim3(8,8), 256, 0, stream>>>(Wo, WoTh, WoTl, DD, DD);
  // 3. QKV projection (bf16x3 MFMA)
  gemm_mfma3<0,0><<<dim3(12,64), 256, 0, stream>>>(h1hi, h1lo, Bqh, Bql, nullptr, nullptr, qkv, NTOK, 1536, DD);
  // 4a. convert K,V -> hi/lo bf16 (V transposed)
  convert_kv<<<dim3(TSEQ/64, 32), 256, 0, stream>>>(qkv, Khi, Klo, Vthi, Vtlo);
  // 4b. causal flash attention (shuffle-free PV)
  attn_mfma<<<dim3(32, 8), 512, 0, stream>>>(qkv, Khi, Klo, Vthi, Vtlo, attnhi, attnlo);
  // 5. Wo projection + bias + residual -> x1
  gemm_mfma3<1,1><<<dim3(4,64), 256, 0, stream>>>(attnhi, attnlo, WoTh, WoTl, bo, x, x1, NTOK, DD, DD);
  // 6. fused LN2 + router
  routerln_kernel<<<dim3(NTOK/4), 256, 0, stream>>>(x1, ln2g, ln2b, Wg, bg, Wn, bn,
      h2b, idx0, idx1, g0, g1);
  // 7. expert weights -> bf16 transposed
  transp_conv<<<dim3(32,8,NE), 256, 0, stream>>>(W1, W1T, DD, FF);
  transp_conv<<<dim3(8,32,NE), 256, 0, stream>>>(W2, W2T, FF, DD);
  // 8. capacity scan
  route_scan<<<dim3(NE), 256, 0, stream>>>(idx0, idx1, idx_buf, tok_slot);
  // 9+10. expert FFN, all 8 experts per launch (e = flat&7 -> one per XCD);
  //       W1 gathers tokens directly via idx_buf
  gemm_mfma<1,1,1,4,3><<<dim3(8*16*16), 256, 0, stream>>>(
      h2b, W1T, b1, mid, idx_buf, CAPK, FF, DD);
  gemm_mfma<1,0,0,2,3><<<dim3(8*16*4), 256, 0, stream>>>(
      mid, W2T, b2, eoutb, nullptr, CAPK, DD, FF);
  // 11. combine + residual
  combine_kernel<<<dim3(NTOK), 128, 0, stream>>>(x1, eoutb, idx0, idx1, g0, g1, tok_slot, out);
}